// Round 1
// baseline (1435.384 us; speedup 1.0000x reference)
//
#include <hip/hip_runtime.h>
#include <cstdint>
#include <cstddef>

// Problem shape (fixed by setup_inputs): B=8, W=1024, H=8, D=64
#define W  1024
#define NH 8
#define NB 8
#define DH 64
#define BHN (NB*NH)            // 64 batch-heads
#define CTX_ELEMS ((size_t)NB*W*NH*DH)   // 4194304

// ---------- helpers ----------

// monotonic float<->uint mapping so atomicMin/Max on uint == float min/max
__device__ __forceinline__ unsigned enc_f(float f){
  unsigned u = __float_as_uint(f);
  return (u & 0x80000000u) ? ~u : (u | 0x80000000u);
}
__device__ __forceinline__ float dec_f(unsigned k){
  unsigned u = (k & 0x80000000u) ? (k ^ 0x80000000u) : ~k;
  return __uint_as_float(u);
}

// fake-quant: clip(round(x/s)+z, mn, mx); dequant (t-z)*s.  rintf == round-half-even == jnp.round
__device__ __forceinline__ float fq1(float x, float s, float z, float mn, float mx){
  float t = rintf(x / s) + z;
  t = fminf(fmaxf(t, mn), mx);
  return (t - z) * s;
}

// block (256-thread) min/max reduce -> one atomic pair
__device__ __forceinline__ void blk_minmax_atomic(float lmin, float lmax,
                                                  unsigned* smin, unsigned* smax){
  #pragma unroll
  for (int o = 32; o; o >>= 1){
    lmin = fminf(lmin, __shfl_xor(lmin, o));
    lmax = fmaxf(lmax, __shfl_xor(lmax, o));
  }
  __shared__ float wmn[4], wmx[4];
  int wid = threadIdx.x >> 6, lane = threadIdx.x & 63;
  if (lane == 0){ wmn[wid] = lmin; wmx[wid] = lmax; }
  __syncthreads();
  if (threadIdx.x == 0){
    float a = wmn[0], b = wmx[0];
    for (int w = 1; w < (int)(blockDim.x >> 6); ++w){
      a = fminf(a, wmn[w]); b = fmaxf(b, wmx[w]);
    }
    atomicMin(smin, enc_f(a));
    atomicMax(smax, enc_f(b));
  }
}

// ---------- kernels ----------

// slots[0..11]: (min,max) pairs for q,k,v,scores,att,ctx ; init to enc(0.0f)
// (reference clamps min<=0<=max, so 0-init is exactly the reference semantics)
__global__ void init_slots_kernel(unsigned* __restrict__ slots){
  if (threadIdx.x < 12) slots[threadIdx.x] = 0x80000000u;  // enc(0.0f)
}

__global__ __launch_bounds__(256) void minmax3_kernel(const float* __restrict__ q,
                                                      const float* __restrict__ k,
                                                      const float* __restrict__ v,
                                                      unsigned* __restrict__ slots){
  const float4* p = (const float4*)(blockIdx.y == 0 ? q : (blockIdx.y == 1 ? k : v));
  float lmin = 0.f, lmax = 0.f;
  const int n4 = (int)(CTX_ELEMS / 4);
  for (int i = blockIdx.x * blockDim.x + threadIdx.x; i < n4; i += gridDim.x * blockDim.x){
    float4 x = p[i];
    lmin = fminf(lmin, fminf(fminf(x.x, x.y), fminf(x.z, x.w)));
    lmax = fmaxf(lmax, fmaxf(fmaxf(x.x, x.y), fmaxf(x.z, x.w)));
  }
  blk_minmax_atomic(lmin, lmax, slots + 2*blockIdx.y, slots + 2*blockIdx.y + 1);
}

// params[4t..4t+3] = scale, zp, qmin, qmax for tensor t (0=q,1=k,2=v,3=scores,4=att,5=ctx)
__global__ void finalize_kernel(const unsigned* __restrict__ slots, float* __restrict__ params,
                                const int* __restrict__ bits_p, int t0, int t1){
  if (threadIdx.x == 0 && blockIdx.x == 0){
    int bits = *bits_p;
    float qmn = -(float)(1 << (bits - 1));
    float qmx = (float)((1 << (bits - 1)) - 1);
    for (int t = t0; t < t1; ++t){
      float mn = dec_f(slots[2*t]);
      float mx = dec_f(slots[2*t + 1]);
      float sc = fmaxf((mx - mn) / (qmx - qmn), 1e-8f);
      float zp = fminf(fmaxf(rintf(qmn - mn / sc), qmn), qmx);
      params[4*t + 0] = sc; params[4*t + 1] = zp;
      params[4*t + 2] = qmn; params[4*t + 3] = qmx;
    }
  }
}

// scores[bh,i,j] = 0.125 * sum_d qf[b,i,h,d]*kf[b,j,h,d]; write raw scores to att region,
// reduce global min/max into slots[6],[7]
__global__ __launch_bounds__(256) void gemm1_kernel(const float* __restrict__ qg,
                                                    const float* __restrict__ kg,
                                                    const float* __restrict__ params,
                                                    float* __restrict__ sc_out,
                                                    unsigned* __restrict__ slots){
  __shared__ float Qs[64][72];   // [d][row], padded
  __shared__ float Ks[64][72];
  const int jt = blockIdx.x, it = blockIdx.y, bh = blockIdx.z;
  const int b = bh >> 3, h = bh & 7;
  const int i0 = it << 6, j0 = jt << 6;
  const int t = threadIdx.x;
  const int row = t & 63, ch = (t >> 6) << 4;
  const float sq = params[0], zq = params[1], qmn = params[2], qmx = params[3];
  const float sk = params[4], zk = params[5];

  const float* qp = qg + (((size_t)(b * W + i0 + row) * NH + h) * DH + ch);
  const float* kp = kg + (((size_t)(b * W + j0 + row) * NH + h) * DH + ch);
  #pragma unroll
  for (int j4 = 0; j4 < 4; ++j4){
    float4 x = *(const float4*)(qp + j4 * 4);
    Qs[ch + j4*4 + 0][row] = fq1(x.x, sq, zq, qmn, qmx);
    Qs[ch + j4*4 + 1][row] = fq1(x.y, sq, zq, qmn, qmx);
    Qs[ch + j4*4 + 2][row] = fq1(x.z, sq, zq, qmn, qmx);
    Qs[ch + j4*4 + 3][row] = fq1(x.w, sq, zq, qmn, qmx);
    float4 y = *(const float4*)(kp + j4 * 4);
    Ks[ch + j4*4 + 0][row] = fq1(y.x, sk, zk, qmn, qmx);
    Ks[ch + j4*4 + 1][row] = fq1(y.y, sk, zk, qmn, qmx);
    Ks[ch + j4*4 + 2][row] = fq1(y.z, sk, zk, qmn, qmx);
    Ks[ch + j4*4 + 3][row] = fq1(y.w, sk, zk, qmn, qmx);
  }
  __syncthreads();

  const int tx = t & 15, ty = t >> 4;
  float acc[4][4] = {};
  #pragma unroll 8
  for (int kk = 0; kk < 64; ++kk){
    float4 a  = *(const float4*)&Qs[kk][ty << 2];
    float4 bb = *(const float4*)&Ks[kk][tx << 2];
    acc[0][0] = fmaf(a.x, bb.x, acc[0][0]); acc[0][1] = fmaf(a.x, bb.y, acc[0][1]);
    acc[0][2] = fmaf(a.x, bb.z, acc[0][2]); acc[0][3] = fmaf(a.x, bb.w, acc[0][3]);
    acc[1][0] = fmaf(a.y, bb.x, acc[1][0]); acc[1][1] = fmaf(a.y, bb.y, acc[1][1]);
    acc[1][2] = fmaf(a.y, bb.z, acc[1][2]); acc[1][3] = fmaf(a.y, bb.w, acc[1][3]);
    acc[2][0] = fmaf(a.z, bb.x, acc[2][0]); acc[2][1] = fmaf(a.z, bb.y, acc[2][1]);
    acc[2][2] = fmaf(a.z, bb.z, acc[2][2]); acc[2][3] = fmaf(a.z, bb.w, acc[2][3]);
    acc[3][0] = fmaf(a.w, bb.x, acc[3][0]); acc[3][1] = fmaf(a.w, bb.y, acc[3][1]);
    acc[3][2] = fmaf(a.w, bb.z, acc[3][2]); acc[3][3] = fmaf(a.w, bb.w, acc[3][3]);
  }

  float lmin = 0.f, lmax = 0.f;
  #pragma unroll
  for (int ri = 0; ri < 4; ++ri){
    float4 o;
    o.x = acc[ri][0] * 0.125f; o.y = acc[ri][1] * 0.125f;
    o.z = acc[ri][2] * 0.125f; o.w = acc[ri][3] * 0.125f;
    lmin = fminf(lmin, fminf(fminf(o.x, o.y), fminf(o.z, o.w)));
    lmax = fmaxf(lmax, fmaxf(fmaxf(o.x, o.y), fmaxf(o.z, o.w)));
    *(float4*)(sc_out + ((size_t)bh << 20) + (size_t)(i0 + (ty << 2) + ri) * W + j0 + (tx << 2)) = o;
  }
  blk_minmax_atomic(lmin, lmax, slots + 6, slots + 7);
}

// per-row: fake-quant scores, softmax, write att in place; global att max -> slot 9
__global__ __launch_bounds__(256) void softmax_kernel(float* __restrict__ att,
                                                      const float* __restrict__ params,
                                                      unsigned* __restrict__ slots){
  const int wid = threadIdx.x >> 6, lane = threadIdx.x & 63;
  const size_t rowid = ((size_t)blockIdx.x << 2) + wid;   // 65536 rows
  float* rp = att + (rowid << 10);
  const float ss = params[12], zs = params[13], smn = params[14], smx = params[15];

  float v[16];
  #pragma unroll
  for (int w = 0; w < 4; ++w){
    float4 x = *(const float4*)(rp + (((size_t)(w << 6) + lane) << 2));
    v[w*4+0] = fq1(x.x, ss, zs, smn, smx);
    v[w*4+1] = fq1(x.y, ss, zs, smn, smx);
    v[w*4+2] = fq1(x.z, ss, zs, smn, smx);
    v[w*4+3] = fq1(x.w, ss, zs, smn, smx);
  }
  float m = v[0];
  #pragma unroll
  for (int i = 1; i < 16; ++i) m = fmaxf(m, v[i]);
  #pragma unroll
  for (int o = 32; o; o >>= 1) m = fmaxf(m, __shfl_xor(m, o));
  float sum = 0.f;
  #pragma unroll
  for (int i = 0; i < 16; ++i){ v[i] = expf(v[i] - m); sum += v[i]; }
  #pragma unroll
  for (int o = 32; o; o >>= 1) sum += __shfl_xor(sum, o);
  #pragma unroll
  for (int w = 0; w < 4; ++w){
    float4 x;
    x.x = v[w*4+0] / sum; x.y = v[w*4+1] / sum;
    x.z = v[w*4+2] / sum; x.w = v[w*4+3] / sum;
    *(float4*)(rp + (((size_t)(w << 6) + lane) << 2)) = x;
  }
  // row max of softmax is exactly 1/sum (element with v==m gives expf(0)==1)
  if (lane == 0) atomicMax(slots + 9, enc_f(1.0f / sum));
}

// fused: fake-quant att (write att_q in place) + context = att_q @ vf ; raw ctx out,
// minmax ctx -> slots[10],[11]
__global__ __launch_bounds__(256) void gemm2_kernel(float* __restrict__ att,
                                                    const float* __restrict__ vg,
                                                    const float* __restrict__ params,
                                                    float* __restrict__ ctx,
                                                    unsigned* __restrict__ slots){
  __shared__ float As[64][72];   // [k][row]
  __shared__ float Vs[64][72];   // [k][d]
  const int it = blockIdx.x, bh = blockIdx.y;
  const int b = bh >> 3, h = bh & 7;
  const int i0 = it << 6;
  const int t = threadIdx.x;
  const int row = t & 63, ch = (t >> 6) << 4;
  const int tx = t & 15, ty = t >> 4;
  const float sa = params[16], za = params[17], amn = params[18], amx = params[19];
  const float sv = params[8],  zv = params[9];
  const float qmn = params[10], qmx = params[11];

  float acc[4][4] = {};
  for (int k0 = 0; k0 < W; k0 += 64){
    float* ap = att + ((size_t)bh << 20) + (size_t)(i0 + row) * W + k0 + ch;
    const float* vp = vg + (((size_t)(b * W + k0 + row) * NH + h) * DH + ch);
    #pragma unroll
    for (int j4 = 0; j4 < 4; ++j4){
      float4 x = *(const float4*)(ap + j4 * 4);
      float4 y;
      y.x = fq1(x.x, sa, za, amn, amx);
      y.y = fq1(x.y, sa, za, amn, amx);
      y.z = fq1(x.z, sa, za, amn, amx);
      y.w = fq1(x.w, sa, za, amn, amx);
      *(float4*)(ap + j4 * 4) = y;                 // att_q output (in place)
      As[ch + j4*4 + 0][row] = y.x;
      As[ch + j4*4 + 1][row] = y.y;
      As[ch + j4*4 + 2][row] = y.z;
      As[ch + j4*4 + 3][row] = y.w;
      float4 vv = *(const float4*)(vp + j4 * 4);
      float4 vq;
      vq.x = fq1(vv.x, sv, zv, qmn, qmx);
      vq.y = fq1(vv.y, sv, zv, qmn, qmx);
      vq.z = fq1(vv.z, sv, zv, qmn, qmx);
      vq.w = fq1(vv.w, sv, zv, qmn, qmx);
      *(float4*)&Vs[row][ch + j4*4] = vq;
    }
    __syncthreads();
    #pragma unroll 8
    for (int kk = 0; kk < 64; ++kk){
      float4 a  = *(const float4*)&As[kk][ty << 2];
      float4 bb = *(const float4*)&Vs[kk][tx << 2];
      acc[0][0] = fmaf(a.x, bb.x, acc[0][0]); acc[0][1] = fmaf(a.x, bb.y, acc[0][1]);
      acc[0][2] = fmaf(a.x, bb.z, acc[0][2]); acc[0][3] = fmaf(a.x, bb.w, acc[0][3]);
      acc[1][0] = fmaf(a.y, bb.x, acc[1][0]); acc[1][1] = fmaf(a.y, bb.y, acc[1][1]);
      acc[1][2] = fmaf(a.y, bb.z, acc[1][2]); acc[1][3] = fmaf(a.y, bb.w, acc[1][3]);
      acc[2][0] = fmaf(a.z, bb.x, acc[2][0]); acc[2][1] = fmaf(a.z, bb.y, acc[2][1]);
      acc[2][2] = fmaf(a.z, bb.z, acc[2][2]); acc[2][3] = fmaf(a.z, bb.w, acc[2][3]);
      acc[3][0] = fmaf(a.w, bb.x, acc[3][0]); acc[3][1] = fmaf(a.w, bb.y, acc[3][1]);
      acc[3][2] = fmaf(a.w, bb.z, acc[3][2]); acc[3][3] = fmaf(a.w, bb.w, acc[3][3]);
    }
    __syncthreads();
  }

  float lmin = 0.f, lmax = 0.f;
  #pragma unroll
  for (int ri = 0; ri < 4; ++ri){
    float4 o; o.x = acc[ri][0]; o.y = acc[ri][1]; o.z = acc[ri][2]; o.w = acc[ri][3];
    lmin = fminf(lmin, fminf(fminf(o.x, o.y), fminf(o.z, o.w)));
    lmax = fmaxf(lmax, fmaxf(fmaxf(o.x, o.y), fmaxf(o.z, o.w)));
    *(float4*)(ctx + (((size_t)(b * W + i0 + (ty << 2) + ri)) * NH + h) * DH + (tx << 2)) = o;
  }
  blk_minmax_atomic(lmin, lmax, slots + 10, slots + 11);
}

__global__ __launch_bounds__(256) void quantctx_kernel(float* __restrict__ ctx,
                                                       const float* __restrict__ params){
  const float s = params[20], z = params[21], mn = params[22], mx = params[23];
  size_t i = (size_t)blockIdx.x * blockDim.x + threadIdx.x;   // float4 index
  float4* p = (float4*)ctx;
  float4 x = p[i];
  x.x = fq1(x.x, s, z, mn, mx);
  x.y = fq1(x.y, s, z, mn, mx);
  x.z = fq1(x.z, s, z, mn, mx);
  x.w = fq1(x.w, s, z, mn, mx);
  p[i] = x;
}

// ---------- launch ----------

extern "C" void kernel_launch(void* const* d_in, const int* in_sizes, int n_in,
                              void* d_out, int out_size, void* d_ws, size_t ws_size,
                              hipStream_t stream){
  const float* q = (const float*)d_in[0];
  const float* k = (const float*)d_in[1];
  const float* v = (const float*)d_in[2];
  const int* bits = (const int*)d_in[3];
  float* ctx = (float*)d_out;
  float* att = (float*)d_out + CTX_ELEMS;          // 64M floats: scores -> att -> att_q
  unsigned* slots = (unsigned*)d_ws;               // 12 uints
  float* params = (float*)((char*)d_ws + 64);      // 24 floats

  hipLaunchKernelGGL(init_slots_kernel, dim3(1), dim3(16), 0, stream, slots);
  hipLaunchKernelGGL(minmax3_kernel, dim3(512, 3), dim3(256), 0, stream, q, k, v, slots);
  hipLaunchKernelGGL(finalize_kernel, dim3(1), dim3(1), 0, stream, slots, params, bits, 0, 3);
  hipLaunchKernelGGL(gemm1_kernel, dim3(16, 16, BHN), dim3(256), 0, stream, q, k, params, att, slots);
  hipLaunchKernelGGL(finalize_kernel, dim3(1), dim3(1), 0, stream, slots, params, bits, 3, 4);
  hipLaunchKernelGGL(softmax_kernel, dim3(16384), dim3(256), 0, stream, att, params, slots);
  hipLaunchKernelGGL(finalize_kernel, dim3(1), dim3(1), 0, stream, slots, params, bits, 4, 5);
  hipLaunchKernelGGL(gemm2_kernel, dim3(16, BHN), dim3(256), 0, stream, att, v, params, ctx, slots);
  hipLaunchKernelGGL(finalize_kernel, dim3(1), dim3(1), 0, stream, slots, params, bits, 5, 6);
  hipLaunchKernelGGL(quantctx_kernel, dim3(4096), dim3(256), 0, stream, ctx, params);
}

// Round 2
// 663.803 us; speedup vs baseline: 2.1624x; 2.1624x over previous
//
#include <hip/hip_runtime.h>
#include <cstdint>
#include <cstddef>

// Problem shape (fixed by setup_inputs): B=8, W=1024, H=8, D=64
#define W  1024
#define NH 8
#define NB 8
#define DH 64
#define BHN (NB*NH)                      // 64 batch-heads
#define CTX_ELEMS ((size_t)NB*W*NH*DH)   // 4194304
#define NS 64                            // atomic spread width

// ---------- helpers ----------

// monotonic float<->uint mapping so atomicMin/Max on uint == float min/max
__device__ __forceinline__ unsigned enc_f(float f){
  unsigned u = __float_as_uint(f);
  return (u & 0x80000000u) ? ~u : (u | 0x80000000u);
}
__device__ __forceinline__ float dec_f(unsigned k){
  unsigned u = (k & 0x80000000u) ? (k ^ 0x80000000u) : ~k;
  return __uint_as_float(u);
}

// fake-quant: clip(round(x/s)+z, mn, mx); dequant (t-z)*s.  rintf == half-even == jnp.round
__device__ __forceinline__ float fq1(float x, float s, float z, float mn, float mx){
  float t = rintf(x / s) + z;
  t = fminf(fmaxf(t, mn), mx);
  return (t - z) * s;
}

// slot layout in ws: spread[(2*t+0)*NS + i] = min copies, [(2*t+1)*NS + i] = max copies
__device__ __forceinline__ unsigned* slot_min(unsigned* s, int t){ return s + (size_t)(2*t)*NS; }
__device__ __forceinline__ unsigned* slot_max(unsigned* s, int t){ return s + (size_t)(2*t+1)*NS; }

// block (256-thread) min/max reduce -> one atomic pair (to spread copies)
__device__ __forceinline__ void blk_minmax_atomic(float lmin, float lmax,
                                                  unsigned* smin, unsigned* smax){
  #pragma unroll
  for (int o = 32; o; o >>= 1){
    lmin = fminf(lmin, __shfl_xor(lmin, o));
    lmax = fmaxf(lmax, __shfl_xor(lmax, o));
  }
  __shared__ float wmn[4], wmx[4];
  int wid = threadIdx.x >> 6, lane = threadIdx.x & 63;
  if (lane == 0){ wmn[wid] = lmin; wmx[wid] = lmax; }
  __syncthreads();
  if (threadIdx.x == 0){
    float a = wmn[0], b = wmx[0];
    for (int w = 1; w < (int)(blockDim.x >> 6); ++w){
      a = fminf(a, wmn[w]); b = fmaxf(b, wmx[w]);
    }
    atomicMin(smin, enc_f(a));
    atomicMax(smax, enc_f(b));
  }
}

// ---------- kernels ----------

__global__ void init_slots_kernel(unsigned* __restrict__ slots){
  for (int i = threadIdx.x; i < 6*2*NS; i += blockDim.x)
    slots[i] = 0x80000000u;  // enc(0.0f): reference clamps min<=0<=max
}

__global__ __launch_bounds__(256) void minmax3_kernel(const float* __restrict__ q,
                                                      const float* __restrict__ k,
                                                      const float* __restrict__ v,
                                                      unsigned* __restrict__ slots){
  const float4* p = (const float4*)(blockIdx.y == 0 ? q : (blockIdx.y == 1 ? k : v));
  float lmin = 0.f, lmax = 0.f;
  const int n4 = (int)(CTX_ELEMS / 4);
  for (int i = blockIdx.x * blockDim.x + threadIdx.x; i < n4; i += gridDim.x * blockDim.x){
    float4 x = p[i];
    lmin = fminf(lmin, fminf(fminf(x.x, x.y), fminf(x.z, x.w)));
    lmax = fmaxf(lmax, fmaxf(fmaxf(x.x, x.y), fmaxf(x.z, x.w)));
  }
  const int idx = blockIdx.x & (NS - 1);
  blk_minmax_atomic(lmin, lmax, slot_min(slots, blockIdx.y) + idx, slot_max(slots, blockIdx.y) + idx);
}

// params[4t..4t+3] = scale, zp, qmin, qmax (t: 0=q,1=k,2=v,3=scores,4=att,5=ctx)
__global__ void finalize_kernel(unsigned* __restrict__ slots, float* __restrict__ params,
                                const int* __restrict__ bits_p, int t0, int t1){
  if (threadIdx.x == 0 && blockIdx.x == 0){
    int bits = *bits_p;
    float qmn = -(float)(1 << (bits - 1));
    float qmx = (float)((1 << (bits - 1)) - 1);
    for (int t = t0; t < t1; ++t){
      unsigned* pm = slot_min(slots, t);
      unsigned* px = slot_max(slots, t);
      unsigned em = pm[0], ex = px[0];
      for (int i = 1; i < NS; ++i){
        em = (pm[i] < em) ? pm[i] : em;
        ex = (px[i] > ex) ? px[i] : ex;
      }
      float mn = dec_f(em), mx = dec_f(ex);
      float sc = fmaxf((mx - mn) / (qmx - qmn), 1e-8f);
      float zp = fminf(fmaxf(rintf(qmn - mn / sc), qmn), qmx);
      params[4*t + 0] = sc; params[4*t + 1] = zp;
      params[4*t + 2] = qmn; params[4*t + 3] = qmx;
    }
  }
}

// scores[bh,i,j] = 0.125 * sum_d qf*kf -> att region; minmax -> spread slots t=3
__global__ __launch_bounds__(256) void gemm1_kernel(const float* __restrict__ qg,
                                                    const float* __restrict__ kg,
                                                    const float* __restrict__ params,
                                                    float* __restrict__ sc_out,
                                                    unsigned* __restrict__ slots){
  __shared__ float Qs[64][72];   // [d][row], padded
  __shared__ float Ks[64][72];
  const int jt = blockIdx.x, it = blockIdx.y, bh = blockIdx.z;
  const int b = bh >> 3, h = bh & 7;
  const int i0 = it << 6, j0 = jt << 6;
  const int t = threadIdx.x;
  const int row = t & 63, ch = (t >> 6) << 4;
  const float sq = params[0], zq = params[1], qmn = params[2], qmx = params[3];
  const float sk = params[4], zk = params[5];

  const float* qp = qg + (((size_t)(b * W + i0 + row) * NH + h) * DH + ch);
  const float* kp = kg + (((size_t)(b * W + j0 + row) * NH + h) * DH + ch);
  #pragma unroll
  for (int j4 = 0; j4 < 4; ++j4){
    float4 x = *(const float4*)(qp + j4 * 4);
    Qs[ch + j4*4 + 0][row] = fq1(x.x, sq, zq, qmn, qmx);
    Qs[ch + j4*4 + 1][row] = fq1(x.y, sq, zq, qmn, qmx);
    Qs[ch + j4*4 + 2][row] = fq1(x.z, sq, zq, qmn, qmx);
    Qs[ch + j4*4 + 3][row] = fq1(x.w, sq, zq, qmn, qmx);
    float4 y = *(const float4*)(kp + j4 * 4);
    Ks[ch + j4*4 + 0][row] = fq1(y.x, sk, zk, qmn, qmx);
    Ks[ch + j4*4 + 1][row] = fq1(y.y, sk, zk, qmn, qmx);
    Ks[ch + j4*4 + 2][row] = fq1(y.z, sk, zk, qmn, qmx);
    Ks[ch + j4*4 + 3][row] = fq1(y.w, sk, zk, qmn, qmx);
  }
  __syncthreads();

  const int tx = t & 15, ty = t >> 4;
  float acc[4][4] = {};
  #pragma unroll 8
  for (int kk = 0; kk < 64; ++kk){
    float4 a  = *(const float4*)&Qs[kk][ty << 2];
    float4 bb = *(const float4*)&Ks[kk][tx << 2];
    acc[0][0] = fmaf(a.x, bb.x, acc[0][0]); acc[0][1] = fmaf(a.x, bb.y, acc[0][1]);
    acc[0][2] = fmaf(a.x, bb.z, acc[0][2]); acc[0][3] = fmaf(a.x, bb.w, acc[0][3]);
    acc[1][0] = fmaf(a.y, bb.x, acc[1][0]); acc[1][1] = fmaf(a.y, bb.y, acc[1][1]);
    acc[1][2] = fmaf(a.y, bb.z, acc[1][2]); acc[1][3] = fmaf(a.y, bb.w, acc[1][3]);
    acc[2][0] = fmaf(a.z, bb.x, acc[2][0]); acc[2][1] = fmaf(a.z, bb.y, acc[2][1]);
    acc[2][2] = fmaf(a.z, bb.z, acc[2][2]); acc[2][3] = fmaf(a.z, bb.w, acc[2][3]);
    acc[3][0] = fmaf(a.w, bb.x, acc[3][0]); acc[3][1] = fmaf(a.w, bb.y, acc[3][1]);
    acc[3][2] = fmaf(a.w, bb.z, acc[3][2]); acc[3][3] = fmaf(a.w, bb.w, acc[3][3]);
  }

  float lmin = 0.f, lmax = 0.f;
  #pragma unroll
  for (int ri = 0; ri < 4; ++ri){
    float4 o;
    o.x = acc[ri][0] * 0.125f; o.y = acc[ri][1] * 0.125f;
    o.z = acc[ri][2] * 0.125f; o.w = acc[ri][3] * 0.125f;
    lmin = fminf(lmin, fminf(fminf(o.x, o.y), fminf(o.z, o.w)));
    lmax = fmaxf(lmax, fmaxf(fmaxf(o.x, o.y), fmaxf(o.z, o.w)));
    *(float4*)(sc_out + ((size_t)bh << 20) + (size_t)(i0 + (ty << 2) + ri) * W + j0 + (tx << 2)) = o;
  }
  const int idx = (jt + it * 16 + bh * 256) & (NS - 1);
  blk_minmax_atomic(lmin, lmax, slot_min(slots, 3) + idx, slot_max(slots, 3) + idx);
}

// shared phase: per-row max m and denominator Z over a 64-row tile of fq'ed scores.
// Op order is FIXED so sumpass and gemm2 compute bit-identical m,Z.
__device__ __forceinline__ void row_mz(const float* __restrict__ tile,
                                       float ss, float zs, float smn, float smx,
                                       float (*pm)[64], float (*pz)[64],
                                       float* sm, float* sZ){
  const int t = threadIdx.x, row = t & 63, c = t >> 6, ch = c << 4;
  const float* rp = tile + (size_t)row * W + ch;
  float lm = -INFINITY;
  for (int k0 = 0; k0 < W; k0 += 64){
    #pragma unroll
    for (int j4 = 0; j4 < 4; ++j4){
      float4 x = *(const float4*)(rp + k0 + j4 * 4);
      float a = fq1(x.x, ss, zs, smn, smx);
      float b = fq1(x.y, ss, zs, smn, smx);
      float cc = fq1(x.z, ss, zs, smn, smx);
      float d = fq1(x.w, ss, zs, smn, smx);
      lm = fmaxf(lm, fmaxf(fmaxf(a, b), fmaxf(cc, d)));
    }
  }
  pm[c][row] = lm;
  __syncthreads();
  if (t < 64) sm[t] = fmaxf(fmaxf(pm[0][t], pm[1][t]), fmaxf(pm[2][t], pm[3][t]));
  __syncthreads();
  const float m = sm[row];
  float lz = 0.f;
  for (int k0 = 0; k0 < W; k0 += 64){
    #pragma unroll
    for (int j4 = 0; j4 < 4; ++j4){
      float4 x = *(const float4*)(rp + k0 + j4 * 4);
      lz += expf(fq1(x.x, ss, zs, smn, smx) - m);
      lz += expf(fq1(x.y, ss, zs, smn, smx) - m);
      lz += expf(fq1(x.z, ss, zs, smn, smx) - m);
      lz += expf(fq1(x.w, ss, zs, smn, smx) - m);
    }
  }
  pz[c][row] = lz;
  __syncthreads();
  if (t < 64) sZ[t] = ((pz[0][t] + pz[1][t]) + pz[2][t]) + pz[3][t];
  __syncthreads();
}

// read-only pass: global att max = max over rows of 1/Z -> spread slots t=4 (min stays 0)
__global__ __launch_bounds__(256) void sumpass_kernel(const float* __restrict__ sc,
                                                      const float* __restrict__ params,
                                                      unsigned* __restrict__ slots){
  __shared__ float pm[4][64], pz[4][64], sm[64], sZ[64];
  const int it = blockIdx.x, bh = blockIdx.y;
  const float ss = params[12], zs = params[13], smn = params[14], smx = params[15];
  const float* tile = sc + ((size_t)bh << 20) + (size_t)(it << 6) * W;
  row_mz(tile, ss, zs, smn, smx, pm, pz, sm, sZ);
  const int t = threadIdx.x;
  if (t < 64){
    float r = 1.0f / sZ[t];   // row max of softmax is exactly expf(0)/Z = 1/Z
    #pragma unroll
    for (int o = 32; o; o >>= 1) r = fmaxf(r, __shfl_xor(r, o));
    if (t == 0){
      const int idx = (it + bh * 16) & (NS - 1);
      atomicMax(slot_max(slots, 4) + idx, enc_f(r));
    }
  }
}

// fused: recompute m,Z (phase 1, L2-hot), then per tile: scores -> fq -> exp/Z -> fq = att_q
// (written in place over scores = the att_q output region) + context GEMM; ctx minmax t=5
__global__ __launch_bounds__(256) void gemm2_kernel(float* __restrict__ att,
                                                    const float* __restrict__ vg,
                                                    const float* __restrict__ params,
                                                    float* __restrict__ ctx,
                                                    unsigned* __restrict__ slots){
  __shared__ float As[64][72];   // [k][row]
  __shared__ float Vs[64][72];   // [k][d]
  __shared__ float pm[4][64], pz[4][64], sm[64], sZ[64];
  const int it = blockIdx.x, bh = blockIdx.y;
  const int b = bh >> 3, h = bh & 7;
  const int i0 = it << 6;
  const int t = threadIdx.x;
  const int row = t & 63, ch = (t >> 6) << 4;
  const int tx = t & 15, ty = t >> 4;
  const float ss = params[12], zs = params[13], smn = params[14], smx = params[15];
  const float sa = params[16], za = params[17], amn = params[18], amx = params[19];
  const float sv = params[8],  zv = params[9];
  const float qmn = params[10], qmx = params[11];

  float* tile = att + ((size_t)bh << 20) + (size_t)i0 * W;
  row_mz(tile, ss, zs, smn, smx, pm, pz, sm, sZ);

  float acc[4][4] = {};
  for (int k0 = 0; k0 < W; k0 += 64){
    float* ap = tile + (size_t)row * W + k0 + ch;
    const float* vp = vg + (((size_t)(b * W + k0 + row) * NH + h) * DH + ch);
    const float mrow = sm[row], zrow = sZ[row];
    #pragma unroll
    for (int j4 = 0; j4 < 4; ++j4){
      float4 x = *(const float4*)(ap + j4 * 4);
      float4 y;
      y.x = fq1(expf(fq1(x.x, ss, zs, smn, smx) - mrow) / zrow, sa, za, amn, amx);
      y.y = fq1(expf(fq1(x.y, ss, zs, smn, smx) - mrow) / zrow, sa, za, amn, amx);
      y.z = fq1(expf(fq1(x.z, ss, zs, smn, smx) - mrow) / zrow, sa, za, amn, amx);
      y.w = fq1(expf(fq1(x.w, ss, zs, smn, smx) - mrow) / zrow, sa, za, amn, amx);
      *(float4*)(ap + j4 * 4) = y;                 // att_q output (in place)
      As[ch + j4*4 + 0][row] = y.x;
      As[ch + j4*4 + 1][row] = y.y;
      As[ch + j4*4 + 2][row] = y.z;
      As[ch + j4*4 + 3][row] = y.w;
      float4 vv = *(const float4*)(vp + j4 * 4);
      float4 vq;
      vq.x = fq1(vv.x, sv, zv, qmn, qmx);
      vq.y = fq1(vv.y, sv, zv, qmn, qmx);
      vq.z = fq1(vv.z, sv, zv, qmn, qmx);
      vq.w = fq1(vv.w, sv, zv, qmn, qmx);
      *(float4*)&Vs[row][ch + j4*4] = vq;
    }
    __syncthreads();
    #pragma unroll 8
    for (int kk = 0; kk < 64; ++kk){
      float4 a  = *(const float4*)&As[kk][ty << 2];
      float4 bb = *(const float4*)&Vs[kk][tx << 2];
      acc[0][0] = fmaf(a.x, bb.x, acc[0][0]); acc[0][1] = fmaf(a.x, bb.y, acc[0][1]);
      acc[0][2] = fmaf(a.x, bb.z, acc[0][2]); acc[0][3] = fmaf(a.x, bb.w, acc[0][3]);
      acc[1][0] = fmaf(a.y, bb.x, acc[1][0]); acc[1][1] = fmaf(a.y, bb.y, acc[1][1]);
      acc[1][2] = fmaf(a.y, bb.z, acc[1][2]); acc[1][3] = fmaf(a.y, bb.w, acc[1][3]);
      acc[2][0] = fmaf(a.z, bb.x, acc[2][0]); acc[2][1] = fmaf(a.z, bb.y, acc[2][1]);
      acc[2][2] = fmaf(a.z, bb.z, acc[2][2]); acc[2][3] = fmaf(a.z, bb.w, acc[2][3]);
      acc[3][0] = fmaf(a.w, bb.x, acc[3][0]); acc[3][1] = fmaf(a.w, bb.y, acc[3][1]);
      acc[3][2] = fmaf(a.w, bb.z, acc[3][2]); acc[3][3] = fmaf(a.w, bb.w, acc[3][3]);
    }
    __syncthreads();
  }

  float lmin = 0.f, lmax = 0.f;
  #pragma unroll
  for (int ri = 0; ri < 4; ++ri){
    float4 o; o.x = acc[ri][0]; o.y = acc[ri][1]; o.z = acc[ri][2]; o.w = acc[ri][3];
    lmin = fminf(lmin, fminf(fminf(o.x, o.y), fminf(o.z, o.w)));
    lmax = fmaxf(lmax, fmaxf(fmaxf(o.x, o.y), fmaxf(o.z, o.w)));
    *(float4*)(ctx + (((size_t)(b * W + i0 + (ty << 2) + ri)) * NH + h) * DH + (tx << 2)) = o;
  }
  const int idx = (it + bh * 16) & (NS - 1);
  blk_minmax_atomic(lmin, lmax, slot_min(slots, 5) + idx, slot_max(slots, 5) + idx);
}

__global__ __launch_bounds__(256) void quantctx_kernel(float* __restrict__ ctx,
                                                       const float* __restrict__ params){
  const float s = params[20], z = params[21], mn = params[22], mx = params[23];
  size_t i = (size_t)blockIdx.x * blockDim.x + threadIdx.x;   // float4 index
  float4* p = (float4*)ctx;
  float4 x = p[i];
  x.x = fq1(x.x, s, z, mn, mx);
  x.y = fq1(x.y, s, z, mn, mx);
  x.z = fq1(x.z, s, z, mn, mx);
  x.w = fq1(x.w, s, z, mn, mx);
  p[i] = x;
}

// ---------- launch ----------

extern "C" void kernel_launch(void* const* d_in, const int* in_sizes, int n_in,
                              void* d_out, int out_size, void* d_ws, size_t ws_size,
                              hipStream_t stream){
  const float* q = (const float*)d_in[0];
  const float* k = (const float*)d_in[1];
  const float* v = (const float*)d_in[2];
  const int* bits = (const int*)d_in[3];
  float* ctx = (float*)d_out;
  float* att = (float*)d_out + CTX_ELEMS;          // 64M floats: scores -> att_q (in place)
  unsigned* slots = (unsigned*)d_ws;               // 6*2*64 uints = 3 KB
  float* params = (float*)((char*)d_ws + 4096);    // 24 floats

  hipLaunchKernelGGL(init_slots_kernel, dim3(1), dim3(256), 0, stream, slots);
  hipLaunchKernelGGL(minmax3_kernel, dim3(512, 3), dim3(256), 0, stream, q, k, v, slots);
  hipLaunchKernelGGL(finalize_kernel, dim3(1), dim3(1), 0, stream, slots, params, bits, 0, 3);
  hipLaunchKernelGGL(gemm1_kernel, dim3(16, 16, BHN), dim3(256), 0, stream, q, k, params, att, slots);
  hipLaunchKernelGGL(finalize_kernel, dim3(1), dim3(1), 0, stream, slots, params, bits, 3, 4);
  hipLaunchKernelGGL(sumpass_kernel, dim3(16, BHN), dim3(256), 0, stream, att, params, slots);
  hipLaunchKernelGGL(finalize_kernel, dim3(1), dim3(1), 0, stream, slots, params, bits, 4, 5);
  hipLaunchKernelGGL(gemm2_kernel, dim3(16, BHN), dim3(256), 0, stream, att, v, params, ctx, slots);
  hipLaunchKernelGGL(finalize_kernel, dim3(1), dim3(1), 0, stream, slots, params, bits, 5, 6);
  hipLaunchKernelGGL(quantctx_kernel, dim3(4096), dim3(256), 0, stream, ctx, params);
}

// Round 3
// 426.797 us; speedup vs baseline: 3.3632x; 1.5553x over previous
//
#include <hip/hip_runtime.h>
#include <cstdint>
#include <cstddef>

// Problem shape (fixed by setup_inputs): B=8, W=1024, H=8, D=64
#define W  1024
#define NH 8
#define NB 8
#define DH 64
#define BHN (NB*NH)                      // 64 batch-heads
#define CTX_ELEMS ((size_t)NB*W*NH*DH)   // 4194304
#define NS 64                            // atomic spread width

typedef int v4i __attribute__((ext_vector_type(4)));

// ---------- helpers ----------

__device__ __forceinline__ unsigned enc_f(float f){
  unsigned u = __float_as_uint(f);
  return (u & 0x80000000u) ? ~u : (u | 0x80000000u);
}
__device__ __forceinline__ float dec_f(unsigned k){
  unsigned u = (k & 0x80000000u) ? (k ^ 0x80000000u) : ~k;
  return __uint_as_float(u);
}

// fake-quant: clip(round(x/s)+z, mn, mx); dequant (t-z)*s. rintf == half-even == jnp.round
__device__ __forceinline__ float fq1(float x, float s, float z, float mn, float mx){
  float t = rintf(x / s) + z;
  t = fminf(fmaxf(t, mn), mx);
  return (t - z) * s;
}
// quantize to integer level
__device__ __forceinline__ int qint(float x, float s, float z, float mn, float mx){
  return (int)fminf(fmaxf(rintf(x / s) + z, mn), mx);
}
__device__ __forceinline__ unsigned pack4(int a0, int a1, int a2, int a3){
  return (unsigned)(a0 & 0xff) | ((unsigned)(a1 & 0xff) << 8) |
         ((unsigned)(a2 & 0xff) << 16) | ((unsigned)(a3 & 0xff) << 24);
}

__device__ __forceinline__ unsigned* slot_min(unsigned* s, int t){ return s + (size_t)(2*t)*NS; }
__device__ __forceinline__ unsigned* slot_max(unsigned* s, int t){ return s + (size_t)(2*t+1)*NS; }

__device__ __forceinline__ void blk_minmax_atomic(float lmin, float lmax,
                                                  unsigned* smin, unsigned* smax){
  #pragma unroll
  for (int o = 32; o; o >>= 1){
    lmin = fminf(lmin, __shfl_xor(lmin, o));
    lmax = fmaxf(lmax, __shfl_xor(lmax, o));
  }
  __shared__ float wmn[4], wmx[4];
  int wid = threadIdx.x >> 6, lane = threadIdx.x & 63;
  if (lane == 0){ wmn[wid] = lmin; wmx[wid] = lmax; }
  __syncthreads();
  if (threadIdx.x == 0){
    float a = wmn[0], b = wmx[0];
    for (int w = 1; w < (int)(blockDim.x >> 6); ++w){
      a = fminf(a, wmn[w]); b = fmaxf(b, wmx[w]);
    }
    atomicMin(smin, enc_f(a));
    atomicMax(smax, enc_f(b));
  }
}

__device__ __forceinline__ void blk_iminmax_atomic(int lmin, int lmax, int* gmin, int* gmax){
  #pragma unroll
  for (int o = 32; o; o >>= 1){
    lmin = min(lmin, __shfl_xor(lmin, o));
    lmax = max(lmax, __shfl_xor(lmax, o));
  }
  __shared__ int iwmn[4], iwmx[4];
  int wid = threadIdx.x >> 6, lane = threadIdx.x & 63;
  if (lane == 0){ iwmn[wid] = lmin; iwmx[wid] = lmax; }
  __syncthreads();
  if (threadIdx.x == 0){
    int a = iwmn[0], b = iwmx[0];
    for (int w = 1; w < (int)(blockDim.x >> 6); ++w){
      a = min(a, iwmn[w]); b = max(b, iwmx[w]);
    }
    atomicMin(gmin, a);
    atomicMax(gmax, b);
  }
}

// ---------- kernels ----------

__global__ void init_slots_kernel(unsigned* __restrict__ slots, int* __restrict__ jmn,
                                  int* __restrict__ jmx){
  for (int i = threadIdx.x; i < 6*2*NS; i += blockDim.x)
    slots[i] = 0x80000000u;   // enc(0.0f): reference clamps min<=0<=max
  if (threadIdx.x < NS){
    jmn[threadIdx.x] = 0x7fffffff;
    jmx[threadIdx.x] = (int)0x80000000;
  }
}

__global__ __launch_bounds__(256) void minmax3_kernel(const float* __restrict__ q,
                                                      const float* __restrict__ k,
                                                      const float* __restrict__ v,
                                                      unsigned* __restrict__ slots){
  const float4* p = (const float4*)(blockIdx.y == 0 ? q : (blockIdx.y == 1 ? k : v));
  float lmin = 0.f, lmax = 0.f;
  const int n4 = (int)(CTX_ELEMS / 4);
  for (int i = blockIdx.x * blockDim.x + threadIdx.x; i < n4; i += gridDim.x * blockDim.x){
    float4 x = p[i];
    lmin = fminf(lmin, fminf(fminf(x.x, x.y), fminf(x.z, x.w)));
    lmax = fmaxf(lmax, fmaxf(fmaxf(x.x, x.y), fmaxf(x.z, x.w)));
  }
  const int idx = blockIdx.x & (NS - 1);
  blk_minmax_atomic(lmin, lmax, slot_min(slots, blockIdx.y) + idx, slot_max(slots, blockIdx.y) + idx);
}

// params[4t..4t+3] = scale, zp, qmin, qmax (t: 0=q,1=k,2=v,3=scores,4=att,5=ctx)
__global__ void finalize_kernel(unsigned* __restrict__ slots, int* __restrict__ jmn,
                                int* __restrict__ jmx, float* __restrict__ params,
                                const int* __restrict__ bits_p, int t0, int t1){
  if (threadIdx.x == 0 && blockIdx.x == 0){
    int bits = *bits_p;
    float qmn = -(float)(1 << (bits - 1));
    float qmx = (float)((1 << (bits - 1)) - 1);
    for (int t = t0; t < t1; ++t){
      float mn, mx;
      if (t == 3){
        int em = jmn[0], ex = jmx[0];
        for (int i = 1; i < NS; ++i){ em = min(em, jmn[i]); ex = max(ex, jmx[i]); }
        float cfac = 0.125f * (params[0] * params[4]);   // same expr as gemm1
        mn = fminf(cfac * (float)em, 0.0f);
        mx = fmaxf(cfac * (float)ex, 0.0f);
      } else {
        unsigned* pm = slot_min(slots, t);
        unsigned* px = slot_max(slots, t);
        unsigned em = pm[0], ex = px[0];
        for (int i = 1; i < NS; ++i){
          em = (pm[i] < em) ? pm[i] : em;
          ex = (px[i] > ex) ? px[i] : ex;
        }
        mn = dec_f(em); mx = dec_f(ex);
      }
      float sc = fmaxf((mx - mn) / (qmx - qmn), 1e-8f);
      float zp = fminf(fmaxf(rintf(qmn - mn / sc), qmn), qmx);
      params[4*t + 0] = sc; params[4*t + 1] = zp;
      params[4*t + 2] = qmn; params[4*t + 3] = qmx;
    }
  }
}

// i8-MFMA QK^T: J[i,j] = sum_d (tq-zq)(tk-zk)  (exact int); scores = cfac*J -> fp32 out.
__global__ __launch_bounds__(256) void gemm1_kernel(const float* __restrict__ qg,
                                                    const float* __restrict__ kg,
                                                    const float* __restrict__ params,
                                                    float* __restrict__ sc_out,
                                                    int* __restrict__ jmn,
                                                    int* __restrict__ jmx){
  __shared__ __align__(16) signed char Qs[64][80];
  __shared__ __align__(16) signed char Ks[64][80];
  __shared__ int Sq[64], Sk[64];
  const int jt = blockIdx.x, it = blockIdx.y, bh = blockIdx.z;
  const int b = bh >> 3, h = bh & 7;
  const int i0 = it << 6, j0 = jt << 6;
  const int t = threadIdx.x;
  const float sq = params[0], zq = params[1], qmn = params[2], qmx = params[3];
  const float sk = params[4], zk = params[5];
  if (t < 64){ Sq[t] = 0; Sk[t] = 0; }
  __syncthreads();
  {
    const int r = t >> 2, dq = (t & 3) << 4;
    const float* qp = qg + (((size_t)(b * W + i0 + r) * NH + h) * DH + dq);
    const float* kp = kg + (((size_t)(b * W + j0 + r) * NH + h) * DH + dq);
    int sumq = 0, sumk = 0;
    #pragma unroll
    for (int g = 0; g < 4; ++g){
      float4 x = *(const float4*)(qp + g * 4);
      int a0 = qint(x.x, sq, zq, qmn, qmx);
      int a1 = qint(x.y, sq, zq, qmn, qmx);
      int a2 = qint(x.z, sq, zq, qmn, qmx);
      int a3 = qint(x.w, sq, zq, qmn, qmx);
      sumq += a0 + a1 + a2 + a3;
      *(unsigned*)&Qs[r][dq + g*4] = pack4(a0, a1, a2, a3);
      float4 y = *(const float4*)(kp + g * 4);
      int b0 = qint(y.x, sk, zk, qmn, qmx);
      int b1 = qint(y.y, sk, zk, qmn, qmx);
      int b2 = qint(y.z, sk, zk, qmn, qmx);
      int b3 = qint(y.w, sk, zk, qmn, qmx);
      sumk += b0 + b1 + b2 + b3;
      *(unsigned*)&Ks[r][dq + g*4] = pack4(b0, b1, b2, b3);
    }
    atomicAdd(&Sq[r], sumq);
    atomicAdd(&Sk[r], sumk);
  }
  __syncthreads();

  const int w = t >> 6, lane = t & 63, lr = lane & 15, lg = lane >> 4;
  v4i A = *(const v4i*)&Qs[(w << 4) + lr][lg << 4];
  v4i acc[4];
  #pragma unroll
  for (int tj = 0; tj < 4; ++tj){
    v4i Bv = *(const v4i*)&Ks[(tj << 4) + lr][lg << 4];
    v4i zz = {0, 0, 0, 0};
    acc[tj] = __builtin_amdgcn_mfma_i32_16x16x64_i8(A, Bv, zz, 0, 0, 0);
  }
  const int izq = (int)zq, izk = (int)zk;
  const float cfac = 0.125f * (sq * sk);
  int lmin = 0x7fffffff, lmax = (int)0x80000000;
  #pragma unroll
  for (int tj = 0; tj < 4; ++tj){
    const int j = (tj << 4) + lr;
    #pragma unroll
    for (int r = 0; r < 4; ++r){
      const int i = (w << 4) + (lg << 2) + r;
      int J = acc[tj][r] - izq * Sk[j] - izk * Sq[i] + 64 * izq * izk;
      lmin = min(lmin, J); lmax = max(lmax, J);
      sc_out[((size_t)bh << 20) + (size_t)(i0 + i) * W + j0 + j] = cfac * (float)J;
    }
  }
  const int idx = (jt + it * 16 + bh * 256) & (NS - 1);
  blk_iminmax_atomic(lmin, lmax, jmn + idx, jmx + idx);
}

// shared m,Z over a 64-row tile of fq'ed scores; FIXED op order so both users bit-match.
// thread t covers rows {t>>4 + 16m}, j-offsets (t&15)*4 + 64*cc.
__device__ __forceinline__ void mz_tile(const float* __restrict__ tile,
                                        float ss, float zs, float smn, float smx,
                                        float* sm, float* sZ, float (*scr)[16]){
  const int t = threadIdx.x;
  const int rb = t >> 4, jo = (t & 15) << 2;
  #pragma unroll
  for (int m = 0; m < 4; ++m){
    const int r = rb + (m << 4);
    const float* rp = tile + (size_t)r * W + jo;
    float mx = -INFINITY;
    for (int cc = 0; cc < 16; ++cc){
      float4 x = *(const float4*)(rp + (cc << 6));
      float a = fq1(x.x, ss, zs, smn, smx);
      float b = fq1(x.y, ss, zs, smn, smx);
      float c = fq1(x.z, ss, zs, smn, smx);
      float d = fq1(x.w, ss, zs, smn, smx);
      mx = fmaxf(mx, fmaxf(fmaxf(a, b), fmaxf(c, d)));
    }
    scr[r][t & 15] = mx;
  }
  __syncthreads();
  if (t < 64){
    float mx = scr[t][0];
    #pragma unroll
    for (int c = 1; c < 16; ++c) mx = fmaxf(mx, scr[t][c]);
    sm[t] = mx;
  }
  __syncthreads();
  #pragma unroll
  for (int m = 0; m < 4; ++m){
    const int r = rb + (m << 4);
    const float* rp = tile + (size_t)r * W + jo;
    const float M = sm[r];
    float z = 0.f;
    for (int cc = 0; cc < 16; ++cc){
      float4 x = *(const float4*)(rp + (cc << 6));
      z += expf(fq1(x.x, ss, zs, smn, smx) - M);
      z += expf(fq1(x.y, ss, zs, smn, smx) - M);
      z += expf(fq1(x.z, ss, zs, smn, smx) - M);
      z += expf(fq1(x.w, ss, zs, smn, smx) - M);
    }
    scr[r][t & 15] = z;
  }
  __syncthreads();
  if (t < 64){
    float z = scr[t][0];
    #pragma unroll
    for (int c = 1; c < 16; ++c) z += scr[t][c];
    sZ[t] = z;
  }
  __syncthreads();
}

// per-row m,Z; global att max = max(1/Z) -> spread slots t=4; optionally persist m,Z.
__global__ __launch_bounds__(256) void sumpass_kernel(const float* __restrict__ sc,
                                                      const float* __restrict__ params,
                                                      unsigned* __restrict__ slots,
                                                      float2* __restrict__ mz){
  __shared__ float sm[64], sZ[64];
  __shared__ float scr[64][16];
  const int it = blockIdx.x, bh = blockIdx.y;
  const int i0 = it << 6;
  const float ss = params[12], zs = params[13], smn = params[14], smx = params[15];
  const float* tile = sc + ((size_t)bh << 20) + (size_t)i0 * W;
  mz_tile(tile, ss, zs, smn, smx, sm, sZ, scr);
  const int t = threadIdx.x;
  if (t < 64){
    float r = 1.0f / sZ[t];          // row max of softmax = expf(0)/Z = 1/Z exactly
    #pragma unroll
    for (int o = 32; o; o >>= 1) r = fmaxf(r, __shfl_xor(r, o));
    if (t == 0){
      const int idx = (it + bh * 16) & (NS - 1);
      atomicMax(slot_max(slots, 4) + idx, enc_f(r));
    }
    if (mz) mz[((size_t)bh << 10) + i0 + t] = make_float2(sm[t], sZ[t]);
  }
}

// fused: scores -> fq -> exp*invZ -> fq = att_q (fp32, in place) + i8-MFMA PV GEMM.
template<bool HAVE_MZ>
__global__ __launch_bounds__(256) void gemm2_kernel(float* __restrict__ att,
                                                    const float* __restrict__ vg,
                                                    const float* __restrict__ params,
                                                    float* __restrict__ ctx,
                                                    unsigned* __restrict__ slots,
                                                    const float2* __restrict__ mz){
  __shared__ __align__(16) signed char As[64][80];
  __shared__ __align__(16) signed char Vs[64][1040];   // [d][j], padded stride
  __shared__ int RowA[64], ColV[64];
  __shared__ float sm[64], sinvZ[64];
  __shared__ float scr[64][16];
  const int it = blockIdx.x, bh = blockIdx.y;
  const int b = bh >> 3, h = bh & 7;
  const int i0 = it << 6;
  const int t = threadIdx.x;
  const float ss = params[12], zs = params[13], smn = params[14], smx = params[15];
  const float sa = params[16], za = params[17], amn = params[18], amx = params[19];
  const float sv = params[8],  zv = params[9], qmn = params[10], qmx = params[11];
  float* tile = att + ((size_t)bh << 20) + (size_t)i0 * W;

  // ---- V stage (once): thread j = t&63, dbase = (t>>6)*16; Vs transposed [d][j]
  {
    const int j = t & 63, dbase = (t >> 6) << 4;
    int cv[16];
    #pragma unroll
    for (int dd = 0; dd < 16; ++dd) cv[dd] = 0;
    for (int cc = 0; cc < 16; ++cc){
      const float* vp = vg + (((size_t)(b * W + (cc << 6) + j) * NH + h) * DH + dbase);
      #pragma unroll
      for (int g = 0; g < 4; ++g){
        float4 x = *(const float4*)(vp + g * 4);
        int a0 = qint(x.x, sv, zv, qmn, qmx);
        int a1 = qint(x.y, sv, zv, qmn, qmx);
        int a2 = qint(x.z, sv, zv, qmn, qmx);
        int a3 = qint(x.w, sv, zv, qmn, qmx);
        Vs[dbase + g*4 + 0][(cc << 6) + j] = (signed char)a0;
        Vs[dbase + g*4 + 1][(cc << 6) + j] = (signed char)a1;
        Vs[dbase + g*4 + 2][(cc << 6) + j] = (signed char)a2;
        Vs[dbase + g*4 + 3][(cc << 6) + j] = (signed char)a3;
        cv[g*4 + 0] += a0; cv[g*4 + 1] += a1; cv[g*4 + 2] += a2; cv[g*4 + 3] += a3;
      }
    }
    #pragma unroll
    for (int dd = 0; dd < 16; ++dd){
      int v = cv[dd];
      #pragma unroll
      for (int o = 32; o; o >>= 1) v += __shfl_xor(v, o);
      if ((t & 63) == 0) ColV[dbase + dd] = v;
    }
  }
  if (t < 64) RowA[t] = 0;

  // ---- m, Z
  if (HAVE_MZ){
    if (t < 64){
      float2 p = mz[((size_t)bh << 10) + i0 + t];
      sm[t] = p.x; sinvZ[t] = 1.0f / p.y;
    }
  } else {
    mz_tile(tile, ss, zs, smn, smx, sm, sinvZ, scr);   // sinvZ holds raw Z
    if (t < 64) sinvZ[t] = 1.0f / sinvZ[t];
  }
  __syncthreads();

  // ---- phase 2: transform + MFMA per 64-wide chunk
  const int rb = t >> 4, jo = (t & 15) << 2;
  const int w = t >> 6, lane = t & 63, lr = lane & 15, lg = lane >> 4;
  const float inv_sa = 1.0f / sa;
  int rA[4] = {0, 0, 0, 0};
  v4i acc[4];
  #pragma unroll
  for (int tj = 0; tj < 4; ++tj){ v4i zz = {0,0,0,0}; acc[tj] = zz; }

  for (int cc = 0; cc < 16; ++cc){
    const int k0 = cc << 6;
    #pragma unroll
    for (int m = 0; m < 4; ++m){
      const int r = rb + (m << 4);
      float* ap = tile + (size_t)r * W + k0 + jo;
      float4 x = *(const float4*)ap;
      const float M = sm[r], iZ = sinvZ[r];
      float p0 = expf(fq1(x.x, ss, zs, smn, smx) - M) * iZ;
      float p1 = expf(fq1(x.y, ss, zs, smn, smx) - M) * iZ;
      float p2 = expf(fq1(x.z, ss, zs, smn, smx) - M) * iZ;
      float p3 = expf(fq1(x.w, ss, zs, smn, smx) - M) * iZ;
      float t0 = fminf(fmaxf(rintf(p0 * inv_sa) + za, amn), amx);
      float t1 = fminf(fmaxf(rintf(p1 * inv_sa) + za, amn), amx);
      float t2 = fminf(fmaxf(rintf(p2 * inv_sa) + za, amn), amx);
      float t3 = fminf(fmaxf(rintf(p3 * inv_sa) + za, amn), amx);
      float4 y;
      y.x = (t0 - za) * sa; y.y = (t1 - za) * sa;
      y.z = (t2 - za) * sa; y.w = (t3 - za) * sa;
      *(float4*)ap = y;                                   // att_q output (in place)
      int q0 = (int)t0, q1 = (int)t1, q2 = (int)t2, q3 = (int)t3;
      rA[m] += q0 + q1 + q2 + q3;
      *(unsigned*)&As[r][jo] = pack4(q0, q1, q2, q3);
    }
    __syncthreads();
    v4i A = *(const v4i*)&As[(w << 4) + lr][lg << 4];
    #pragma unroll
    for (int tj = 0; tj < 4; ++tj){
      v4i Bv = *(const v4i*)&Vs[(tj << 4) + lr][k0 + (lg << 4)];
      acc[tj] = __builtin_amdgcn_mfma_i32_16x16x64_i8(A, Bv, acc[tj], 0, 0, 0);
    }
    __syncthreads();
  }

  #pragma unroll
  for (int m = 0; m < 4; ++m) atomicAdd(&RowA[rb + (m << 4)], rA[m]);
  __syncthreads();

  const int iza = (int)za, izv = (int)zv;
  const float sav = sa * sv;
  float lmin = 0.f, lmax = 0.f;
  #pragma unroll
  for (int tj = 0; tj < 4; ++tj){
    const int d = (tj << 4) + lr;
    #pragma unroll
    for (int r = 0; r < 4; ++r){
      const int i = (w << 4) + (lg << 2) + r;
      int J = acc[tj][r] - iza * ColV[d] - izv * RowA[i] + 1024 * iza * izv;
      float c = sav * (float)J;
      lmin = fminf(lmin, c); lmax = fmaxf(lmax, c);
      ctx[(((size_t)(b * W + i0 + i)) * NH + h) * DH + d] = c;
    }
  }
  const int idx = (it + bh * 16) & (NS - 1);
  blk_minmax_atomic(lmin, lmax, slot_min(slots, 5) + idx, slot_max(slots, 5) + idx);
}

__global__ __launch_bounds__(256) void quantctx_kernel(float* __restrict__ ctx,
                                                       const float* __restrict__ params){
  const float s = params[20], z = params[21], mn = params[22], mx = params[23];
  size_t i = (size_t)blockIdx.x * blockDim.x + threadIdx.x;   // float4 index
  float4* p = (float4*)ctx;
  float4 x = p[i];
  x.x = fq1(x.x, s, z, mn, mx);
  x.y = fq1(x.y, s, z, mn, mx);
  x.z = fq1(x.z, s, z, mn, mx);
  x.w = fq1(x.w, s, z, mn, mx);
  p[i] = x;
}

// ---------- launch ----------

extern "C" void kernel_launch(void* const* d_in, const int* in_sizes, int n_in,
                              void* d_out, int out_size, void* d_ws, size_t ws_size,
                              hipStream_t stream){
  const float* q = (const float*)d_in[0];
  const float* k = (const float*)d_in[1];
  const float* v = (const float*)d_in[2];
  const int* bits = (const int*)d_in[3];
  float* ctx = (float*)d_out;
  float* att = (float*)d_out + CTX_ELEMS;              // scores -> att_q (in place)
  unsigned* slots = (unsigned*)d_ws;                   // 768 uints (3072 B)
  int* jmn = (int*)((char*)d_ws + 3072);               // 64 ints
  int* jmx = (int*)((char*)d_ws + 3328);               // 64 ints
  float* params = (float*)((char*)d_ws + 3584);        // 24 floats (<4160 B total, known-safe)
  float2* mz = (float2*)((char*)d_ws + 8192);          // 64K rows x 8 B = 512 KB (optional)
  const bool have_mz = ws_size >= (size_t)8192 + (size_t)65536 * 8;
  float2* mzp = have_mz ? mz : (float2*)nullptr;

  hipLaunchKernelGGL(init_slots_kernel, dim3(1), dim3(256), 0, stream, slots, jmn, jmx);
  hipLaunchKernelGGL(minmax3_kernel, dim3(512, 3), dim3(256), 0, stream, q, k, v, slots);
  hipLaunchKernelGGL(finalize_kernel, dim3(1), dim3(1), 0, stream, slots, jmn, jmx, params, bits, 0, 3);
  hipLaunchKernelGGL(gemm1_kernel, dim3(16, 16, BHN), dim3(256), 0, stream, q, k, params, att, jmn, jmx);
  hipLaunchKernelGGL(finalize_kernel, dim3(1), dim3(1), 0, stream, slots, jmn, jmx, params, bits, 3, 4);
  hipLaunchKernelGGL(sumpass_kernel, dim3(16, BHN), dim3(256), 0, stream, att, params, slots, mzp);
  hipLaunchKernelGGL(finalize_kernel, dim3(1), dim3(1), 0, stream, slots, jmn, jmx, params, bits, 4, 5);
  if (have_mz)
    hipLaunchKernelGGL(gemm2_kernel<true>, dim3(16, BHN), dim3(256), 0, stream, att, v, params, ctx, slots, mzp);
  else
    hipLaunchKernelGGL(gemm2_kernel<false>, dim3(16, BHN), dim3(256), 0, stream, att, v, params, ctx, slots, mzp);
  hipLaunchKernelGGL(finalize_kernel, dim3(1), dim3(1), 0, stream, slots, jmn, jmx, params, bits, 5, 6);
  hipLaunchKernelGGL(quantctx_kernel, dim3(4096), dim3(256), 0, stream, ctx, params);
}

// Round 5
// 313.133 us; speedup vs baseline: 4.5839x; 1.3630x over previous
//
#include <hip/hip_runtime.h>
#include <cstdint>
#include <cstddef>

// Problem shape (fixed by setup_inputs): B=8, W=1024, H=8, D=64
#define W  1024
#define NH 8
#define NB 8
#define DH 64
#define BHN (NB*NH)                      // 64 batch-heads
#define CTX_ELEMS ((size_t)NB*W*NH*DH)   // 4194304
#define NS 64                            // atomic spread width
#define ROWF 512                         // row stride in floats (NH*DH)

typedef int v4i __attribute__((ext_vector_type(4)));

// ---------- helpers ----------

__device__ __forceinline__ unsigned enc_f(float f){
  unsigned u = __float_as_uint(f);
  return (u & 0x80000000u) ? ~u : (u | 0x80000000u);
}
__device__ __forceinline__ float dec_f(unsigned k){
  unsigned u = (k & 0x80000000u) ? (k ^ 0x80000000u) : ~k;
  return __uint_as_float(u);
}

__device__ __forceinline__ float fq1(float x, float s, float z, float mn, float mx){
  float t = rintf(x / s) + z;
  t = fminf(fmaxf(t, mn), mx);
  return (t - z) * s;
}
__device__ __forceinline__ int qint(float x, float s, float z, float mn, float mx){
  return (int)fminf(fmaxf(rintf(x / s) + z, mn), mx);
}
__device__ __forceinline__ unsigned pack4(int a0, int a1, int a2, int a3){
  return (unsigned)(a0 & 0xff) | ((unsigned)(a1 & 0xff) << 8) |
         ((unsigned)(a2 & 0xff) << 16) | ((unsigned)(a3 & 0xff) << 24);
}

__device__ __forceinline__ unsigned* slot_min(unsigned* s, int t){ return s + (size_t)(2*t)*NS; }
__device__ __forceinline__ unsigned* slot_max(unsigned* s, int t){ return s + (size_t)(2*t+1)*NS; }

__device__ __forceinline__ void blk_minmax_atomic(float lmin, float lmax,
                                                  unsigned* smin, unsigned* smax){
  #pragma unroll
  for (int o = 32; o; o >>= 1){
    lmin = fminf(lmin, __shfl_xor(lmin, o));
    lmax = fmaxf(lmax, __shfl_xor(lmax, o));
  }
  __shared__ float wmn[4], wmx[4];
  int wid = threadIdx.x >> 6, lane = threadIdx.x & 63;
  if (lane == 0){ wmn[wid] = lmin; wmx[wid] = lmax; }
  __syncthreads();
  if (threadIdx.x == 0){
    float a = wmn[0], b = wmx[0];
    for (int w = 1; w < (int)(blockDim.x >> 6); ++w){
      a = fminf(a, wmn[w]); b = fmaxf(b, wmx[w]);
    }
    atomicMin(smin, enc_f(a));
    atomicMax(smax, enc_f(b));
  }
}

__device__ __forceinline__ void blk_iminmax_atomic(int lmin, int lmax, int* gmin, int* gmax){
  #pragma unroll
  for (int o = 32; o; o >>= 1){
    lmin = min(lmin, __shfl_xor(lmin, o));
    lmax = max(lmax, __shfl_xor(lmax, o));
  }
  __shared__ int iwmn[4], iwmx[4];
  int wid = threadIdx.x >> 6, lane = threadIdx.x & 63;
  if (lane == 0){ iwmn[wid] = lmin; iwmx[wid] = lmax; }
  __syncthreads();
  if (threadIdx.x == 0){
    int a = iwmn[0], b = iwmx[0];
    for (int w = 1; w < (int)(blockDim.x >> 6); ++w){
      a = min(a, iwmn[w]); b = max(b, iwmx[w]);
    }
    atomicMin(gmin, a);
    atomicMax(gmax, b);
  }
}

// stage a 64-row x 64-d fp32 tile -> int8 LDS [row][d] (+row sums via 4-lane shfl)
__device__ __forceinline__ void stage_tile(const float* __restrict__ rowptr,
                                           signed char (*S)[80], int* __restrict__ Ssum,
                                           float s, float z, float mn, float mx, int t){
  const int rr = t >> 2, dq = (t & 3) << 4;
  const float* p = rowptr + (size_t)rr * ROWF + dq;
  int part = 0;
  #pragma unroll
  for (int g = 0; g < 4; ++g){
    float4 x = *(const float4*)(p + g * 4);
    int a0 = qint(x.x, s, z, mn, mx), a1 = qint(x.y, s, z, mn, mx);
    int a2 = qint(x.z, s, z, mn, mx), a3 = qint(x.w, s, z, mn, mx);
    part += a0 + a1 + a2 + a3;
    *(unsigned*)&S[rr][dq + g*4] = pack4(a0, a1, a2, a3);
  }
  int x1 = part + __shfl_xor(part, 1);
  int tot = x1 + __shfl_xor(x1, 2);
  if ((t & 3) == 0) Ssum[rr] = tot;
}

// QK^T MFMA (raw, uncorrected) for one 64x64 chunk; scatter raw acc to Js[i][j]
__device__ __forceinline__ void qk_mfma_to_js(const signed char (*Qs)[80],
                                              const signed char (*Ks)[80],
                                              int (*Js)[68], int t){
  const int w = t >> 6, lane = t & 63, lr = lane & 15, lg = lane >> 4;
  v4i A = *(const v4i*)&Qs[(w << 4) + lr][lg << 4];
  #pragma unroll
  for (int tj = 0; tj < 4; ++tj){
    v4i Bv = *(const v4i*)&Ks[(tj << 4) + lr][lg << 4];
    v4i zz = {0, 0, 0, 0};
    v4i acc = __builtin_amdgcn_mfma_i32_16x16x64_i8(A, Bv, zz, 0, 0, 0);
    #pragma unroll
    for (int r = 0; r < 4; ++r) Js[(w << 4) + (lg << 2) + r][(tj << 4) + lr] = acc[r];
  }
}

// corrected J for (row r, cols jo..jo+3)
__device__ __forceinline__ v4i corrJ(const int (*Js)[68], const int* __restrict__ Sk,
                                     const int* __restrict__ Sq, int r, int jo,
                                     int izq, int izk, int c64){
  v4i J = *(const v4i*)&Js[r][jo];
  v4i s4 = *(const v4i*)&Sk[jo];
  const int sq_ = Sq[r];
  v4i o;
  o[0] = J[0] - izq*s4[0] - izk*sq_ + c64;
  o[1] = J[1] - izq*s4[1] - izk*sq_ + c64;
  o[2] = J[2] - izq*s4[2] - izk*sq_ + c64;
  o[3] = J[3] - izq*s4[3] - izk*sq_ + c64;
  return o;
}

// ---------- kernels ----------

__global__ void init_slots_kernel(unsigned* __restrict__ slots, int* __restrict__ jmn,
                                  int* __restrict__ jmx){
  for (int i = threadIdx.x; i < 6*2*NS; i += blockDim.x)
    slots[i] = 0x80000000u;   // enc(0.0f): reference clamps min<=0<=max
  if (threadIdx.x < NS){
    jmn[threadIdx.x] = 0x7fffffff;
    jmx[threadIdx.x] = (int)0x80000000;
  }
}

__global__ __launch_bounds__(256) void minmax3_kernel(const float* __restrict__ q,
                                                      const float* __restrict__ k,
                                                      const float* __restrict__ v,
                                                      unsigned* __restrict__ slots){
  const float4* p = (const float4*)(blockIdx.y == 0 ? q : (blockIdx.y == 1 ? k : v));
  float lmin = 0.f, lmax = 0.f;
  const int n4 = (int)(CTX_ELEMS / 4);
  for (int i = blockIdx.x * blockDim.x + threadIdx.x; i < n4; i += gridDim.x * blockDim.x){
    float4 x = p[i];
    lmin = fminf(lmin, fminf(fminf(x.x, x.y), fminf(x.z, x.w)));
    lmax = fmaxf(lmax, fmaxf(fmaxf(x.x, x.y), fmaxf(x.z, x.w)));
  }
  const int idx = blockIdx.x & (NS - 1);
  blk_minmax_atomic(lmin, lmax, slot_min(slots, blockIdx.y) + idx, slot_max(slots, blockIdx.y) + idx);
}

// params[4t..4t+3] = scale, zp, qmin, qmax (t: 0=q,1=k,2=v,3=scores,4=att,5=ctx)
__global__ void finalize_kernel(unsigned* __restrict__ slots, int* __restrict__ jmn,
                                int* __restrict__ jmx, float* __restrict__ params,
                                const int* __restrict__ bits_p, int t0, int t1){
  if (threadIdx.x == 0 && blockIdx.x == 0){
    int bits = *bits_p;
    float qmn = -(float)(1 << (bits - 1));
    float qmx = (float)((1 << (bits - 1)) - 1);
    for (int t = t0; t < t1; ++t){
      float mn, mx;
      if (t == 3){
        int em = jmn[0], ex = jmx[0];
        for (int i = 1; i < NS; ++i){ em = min(em, jmn[i]); ex = max(ex, jmx[i]); }
        float cfac = 0.125f * (params[0] * params[4]);
        mn = fminf(cfac * (float)em, 0.0f);
        mx = fmaxf(cfac * (float)ex, 0.0f);
      } else {
        unsigned* pm = slot_min(slots, t);
        unsigned* px = slot_max(slots, t);
        unsigned em = pm[0], ex = px[0];
        for (int i = 1; i < NS; ++i){
          em = (pm[i] < em) ? pm[i] : em;
          ex = (px[i] > ex) ? px[i] : ex;
        }
        mn = dec_f(em); mx = dec_f(ex);
      }
      float sc = fmaxf((mx - mn) / (qmx - qmn), 1e-8f);
      float zp = fminf(fmaxf(rintf(qmn - mn / sc), qmn), qmx);
      params[4*t + 0] = sc; params[4*t + 1] = zp;
      params[4*t + 2] = qmn; params[4*t + 3] = qmx;
    }
  }
}

// pass1: global int J min/max (-> jmn/jmx) + per-row Jmax (-> ctx stash d=0). No big writes.
__global__ __launch_bounds__(256) void pass1_kernel(const float* __restrict__ qg,
                                                    const float* __restrict__ kg,
                                                    const float* __restrict__ params,
                                                    float* __restrict__ stash,
                                                    int* __restrict__ jmn,
                                                    int* __restrict__ jmx){
  __shared__ __align__(16) signed char Qs[64][80], Ks[64][80];
  __shared__ __align__(16) int Sq[64], Sk[64];
  __shared__ int Js[64][68];
  __shared__ int scri[64][16];
  const int it = blockIdx.x, bh = blockIdx.y, b = bh >> 3, h = bh & 7;
  const int i0 = it << 6, t = threadIdx.x;
  const float sq = params[0], zq = params[1], qmn = params[2], qmx = params[3];
  const float sk = params[4], zk = params[5];
  const int izq = (int)zq, izk = (int)zk, c64 = 64 * izq * izk;

  stage_tile(qg + ((size_t)(b*W + i0) * NH + h) * DH, Qs, Sq, sq, zq, qmn, qmx, t);

  const int rb = t >> 4, jo = (t & 15) << 2;
  int gmin = 0x7fffffff, gmax = (int)0x80000000;
  int rmax[4];
  #pragma unroll
  for (int m = 0; m < 4; ++m) rmax[m] = (int)0x80000000;

  for (int cc = 0; cc < 16; ++cc){
    __syncthreads();
    stage_tile(kg + ((size_t)(b*W + (cc << 6)) * NH + h) * DH, Ks, Sk, sk, zk, qmn, qmx, t);
    __syncthreads();
    qk_mfma_to_js(Qs, Ks, Js, t);
    __syncthreads();
    #pragma unroll
    for (int m = 0; m < 4; ++m){
      const int r = rb + (m << 4);
      v4i J = corrJ(Js, Sk, Sq, r, jo, izq, izk, c64);
      gmin = min(gmin, min(min(J[0], J[1]), min(J[2], J[3])));
      gmax = max(gmax, max(max(J[0], J[1]), max(J[2], J[3])));
      rmax[m] = max(rmax[m], max(max(J[0], J[1]), max(J[2], J[3])));
    }
  }
  #pragma unroll
  for (int m = 0; m < 4; ++m) scri[rb + (m << 4)][t & 15] = rmax[m];
  __syncthreads();
  if (t < 64){
    int rm = scri[t][0];
    #pragma unroll
    for (int c = 1; c < 16; ++c) rm = max(rm, scri[t][c]);
    stash[((size_t)(b*W + i0 + t) * NH + h) * DH] = __int_as_float(rm);
  }
  const int idx = (it + bh * 16) & (NS - 1);
  blk_iminmax_atomic(gmin, gmax, jmn + idx, jmx + idx);
}

// pass2: per-row Z via LUT (-> ctx stash d=1), global att max (=max 1/Z) -> slot 4.
__global__ __launch_bounds__(256) void pass2_kernel(const float* __restrict__ qg,
                                                    const float* __restrict__ kg,
                                                    const float* __restrict__ params,
                                                    float* __restrict__ stash,
                                                    unsigned* __restrict__ slots){
  __shared__ __align__(16) signed char Qs[64][80], Ks[64][80];
  __shared__ __align__(16) int Sq[64], Sk[64];
  __shared__ int Js[64][68];
  __shared__ float LUT[256];
  __shared__ int tmaxs[64];
  __shared__ float scr[64][16];
  const int it = blockIdx.x, bh = blockIdx.y, b = bh >> 3, h = bh & 7;
  const int i0 = it << 6, t = threadIdx.x;
  const float sq = params[0], zq = params[1], qmn = params[2], qmx = params[3];
  const float sk = params[4], zk = params[5];
  const float ss = params[12], zs = params[13], smn = params[14], smx = params[15];
  const int izq = (int)zq, izk = (int)zk, c64 = 64 * izq * izk;
  const float rf = (0.125f * (sq * sk)) / ss;

  LUT[t] = expf(-(float)t * ss);
  if (t < 64){
    int Jm = __float_as_int(stash[((size_t)(b*W + i0 + t) * NH + h) * DH]);
    tmaxs[t] = (int)fminf(fmaxf(rintf((float)Jm * rf) + zs, smn), smx);
  }
  stage_tile(qg + ((size_t)(b*W + i0) * NH + h) * DH, Qs, Sq, sq, zq, qmn, qmx, t);

  const int rb = t >> 4, jo = (t & 15) << 2;
  float zacc[4] = {0.f, 0.f, 0.f, 0.f};

  for (int cc = 0; cc < 16; ++cc){
    __syncthreads();
    stage_tile(kg + ((size_t)(b*W + (cc << 6)) * NH + h) * DH, Ks, Sk, sk, zk, qmn, qmx, t);
    __syncthreads();
    qk_mfma_to_js(Qs, Ks, Js, t);
    __syncthreads();
    #pragma unroll
    for (int m = 0; m < 4; ++m){
      const int r = rb + (m << 4);
      v4i J = corrJ(Js, Sk, Sq, r, jo, izq, izk, c64);
      const int tmx = tmaxs[r];
      int t0 = (int)fminf(fmaxf(rintf((float)J[0] * rf) + zs, smn), smx);
      int t1 = (int)fminf(fmaxf(rintf((float)J[1] * rf) + zs, smn), smx);
      int t2 = (int)fminf(fmaxf(rintf((float)J[2] * rf) + zs, smn), smx);
      int t3 = (int)fminf(fmaxf(rintf((float)J[3] * rf) + zs, smn), smx);
      zacc[m] += LUT[tmx - t0];
      zacc[m] += LUT[tmx - t1];
      zacc[m] += LUT[tmx - t2];
      zacc[m] += LUT[tmx - t3];
    }
  }
  #pragma unroll
  for (int m = 0; m < 4; ++m) scr[rb + (m << 4)][t & 15] = zacc[m];
  __syncthreads();
  float ratt = 0.f;
  if (t < 64){
    float Z = scr[t][0];
    #pragma unroll
    for (int c = 1; c < 16; ++c) Z += scr[t][c];
    stash[((size_t)(b*W + i0 + t) * NH + h) * DH + 1] = Z;
    ratt = 1.0f / Z;                   // row max of softmax = expf(0)/Z = 1/Z exactly
    #pragma unroll
    for (int o = 32; o; o >>= 1) ratt = fmaxf(ratt, __shfl_xor(ratt, o));
    if (t == 0){
      const int idx = (it + bh * 16) & (NS - 1);
      atomicMax(slot_max(slots, 4) + idx, enc_f(ratt));
    }
  }
}

// pass3: recompute J, transform -> att_q (fp32 out, coalesced) + int8 PV-MFMA -> raw ctx.
__global__ __launch_bounds__(256) void pass3_kernel(const float* __restrict__ qg,
                                                    const float* __restrict__ kg,
                                                    const float* __restrict__ vg,
                                                    const float* __restrict__ params,
                                                    float* __restrict__ att,
                                                    float* __restrict__ ctx,
                                                    unsigned* __restrict__ slots){
  __shared__ __align__(16) signed char Qs[64][80], Ks[64][80], Vs[64][80], As[64][80];
  __shared__ __align__(16) int Sq[64], Sk[64];
  __shared__ int Js[64][68];
  __shared__ float LUT[256];
  __shared__ int tmaxs[64];
  __shared__ float iZs[64];
  __shared__ int RowA[64], ColV[64];
  const int it = blockIdx.x, bh = blockIdx.y, b = bh >> 3, h = bh & 7;
  const int i0 = it << 6, t = threadIdx.x;
  const float sq = params[0], zq = params[1], qmn = params[2], qmx = params[3];
  const float sk = params[4], zk = params[5];
  const float sv = params[8], zv = params[9], vmn = params[10], vmx = params[11];
  const float ss = params[12], zs = params[13], smn = params[14], smx = params[15];
  const float sa = params[16], za = params[17], amn = params[18], amx = params[19];
  const int izq = (int)zq, izk = (int)zk, c64 = 64 * izq * izk;
  const int iza = (int)za, izv = (int)zv;
  const float rf = (0.125f * (sq * sk)) / ss;
  const float inv_sa = 1.0f / sa;

  LUT[t] = expf(-(float)t * ss);
  if (t < 64){
    size_t rbase = ((size_t)(b*W + i0 + t) * NH + h) * DH;
    int Jm = __float_as_int(ctx[rbase]);
    tmaxs[t] = (int)fminf(fmaxf(rintf((float)Jm * rf) + zs, smn), smx);
    iZs[t] = 1.0f / ctx[rbase + 1];
    RowA[t] = 0; ColV[t] = 0;
  }
  stage_tile(qg + ((size_t)(b*W + i0) * NH + h) * DH, Qs, Sq, sq, zq, qmn, qmx, t);

  const int rb = t >> 4, jo = (t & 15) << 2;
  const int w = t >> 6, lane = t & 63, lr = lane & 15, lg = lane >> 4;
  const int kkv = t >> 2, d0v = (t & 3) << 4;
  int cv[16];
  #pragma unroll
  for (int dd = 0; dd < 16; ++dd) cv[dd] = 0;
  int rA[4] = {0, 0, 0, 0};
  v4i accPV[4];
  #pragma unroll
  for (int tj = 0; tj < 4; ++tj){ v4i zz = {0,0,0,0}; accPV[tj] = zz; }

  for (int cc = 0; cc < 16; ++cc){
    __syncthreads();
    stage_tile(kg + ((size_t)(b*W + (cc << 6)) * NH + h) * DH, Ks, Sk, sk, zk, qmn, qmx, t);
    {
      const float* vp = vg + ((size_t)(b*W + (cc << 6) + kkv) * NH + h) * DH + d0v;
      #pragma unroll
      for (int g = 0; g < 4; ++g){
        float4 x = *(const float4*)(vp + g * 4);
        int a0 = qint(x.x, sv, zv, vmn, vmx), a1 = qint(x.y, sv, zv, vmn, vmx);
        int a2 = qint(x.z, sv, zv, vmn, vmx), a3 = qint(x.w, sv, zv, vmn, vmx);
        Vs[d0v + g*4 + 0][kkv] = (signed char)a0;
        Vs[d0v + g*4 + 1][kkv] = (signed char)a1;
        Vs[d0v + g*4 + 2][kkv] = (signed char)a2;
        Vs[d0v + g*4 + 3][kkv] = (signed char)a3;
        cv[g*4 + 0] += a0; cv[g*4 + 1] += a1; cv[g*4 + 2] += a2; cv[g*4 + 3] += a3;
      }
    }
    __syncthreads();
    qk_mfma_to_js(Qs, Ks, Js, t);
    __syncthreads();
    #pragma unroll
    for (int m = 0; m < 4; ++m){
      const int r = rb + (m << 4);
      v4i J = corrJ(Js, Sk, Sq, r, jo, izq, izk, c64);
      const int tmx = tmaxs[r];
      const float iZ = iZs[r];
      int t0 = (int)fminf(fmaxf(rintf((float)J[0] * rf) + zs, smn), smx);
      int t1 = (int)fminf(fmaxf(rintf((float)J[1] * rf) + zs, smn), smx);
      int t2 = (int)fminf(fmaxf(rintf((float)J[2] * rf) + zs, smn), smx);
      int t3 = (int)fminf(fmaxf(rintf((float)J[3] * rf) + zs, smn), smx);
      float p0 = LUT[tmx - t0] * iZ, p1 = LUT[tmx - t1] * iZ;
      float p2 = LUT[tmx - t2] * iZ, p3 = LUT[tmx - t3] * iZ;
      float a0f = fminf(fmaxf(rintf(p0 * inv_sa) + za, amn), amx);
      float a1f = fminf(fmaxf(rintf(p1 * inv_sa) + za, amn), amx);
      float a2f = fminf(fmaxf(rintf(p2 * inv_sa) + za, amn), amx);
      float a3f = fminf(fmaxf(rintf(p3 * inv_sa) + za, amn), amx);
      float4 y;
      y.x = (a0f - za) * sa; y.y = (a1f - za) * sa;
      y.z = (a2f - za) * sa; y.w = (a3f - za) * sa;
      *(float4*)(att + ((size_t)bh << 20) + (size_t)(i0 + r) * W + (cc << 6) + jo) = y;
      int q0 = (int)a0f, q1 = (int)a1f, q2 = (int)a2f, q3 = (int)a3f;
      rA[m] += q0 + q1 + q2 + q3;
      *(unsigned*)&As[r][jo] = pack4(q0, q1, q2, q3);
    }
    __syncthreads();
    {
      v4i A2 = *(const v4i*)&As[(w << 4) + lr][lg << 4];
      #pragma unroll
      for (int tj = 0; tj < 4; ++tj){
        v4i B2 = *(const v4i*)&Vs[(tj << 4) + lr][lg << 4];
        accPV[tj] = __builtin_amdgcn_mfma_i32_16x16x64_i8(A2, B2, accPV[tj], 0, 0, 0);
      }
    }
  }

  #pragma unroll
  for (int m = 0; m < 4; ++m) atomicAdd(&RowA[rb + (m << 4)], rA[m]);
  #pragma unroll
  for (int dd = 0; dd < 16; ++dd) atomicAdd(&ColV[d0v + dd], cv[dd]);
  __syncthreads();

  const float sav = sa * sv;
  float lmin = 0.f, lmax = 0.f;
  #pragma unroll
  for (int tj = 0; tj < 4; ++tj){
    const int d = (tj << 4) + lr;
    #pragma unroll
    for (int r = 0; r < 4; ++r){
      const int i = (w << 4) + (lg << 2) + r;
      int Jv = accPV[tj][r] - iza * ColV[d] - izv * RowA[i] + 1024 * iza * izv;
      float c = sav * (float)Jv;
      lmin = fminf(lmin, c); lmax = fmaxf(lmax, c);
      ctx[(((size_t)(b * W + i0 + i)) * NH + h) * DH + d] = c;
    }
  }
  const int idx = (it + bh * 16) & (NS - 1);
  blk_minmax_atomic(lmin, lmax, slot_min(slots, 5) + idx, slot_max(slots, 5) + idx);
}

__global__ __launch_bounds__(256) void quantctx_kernel(float* __restrict__ ctx,
                                                       const float* __restrict__ params){
  const float s = params[20], z = params[21], mn = params[22], mx = params[23];
  size_t i = (size_t)blockIdx.x * blockDim.x + threadIdx.x;   // float4 index
  float4* p = (float4*)ctx;
  float4 x = p[i];
  x.x = fq1(x.x, s, z, mn, mx);
  x.y = fq1(x.y, s, z, mn, mx);
  x.z = fq1(x.z, s, z, mn, mx);
  x.w = fq1(x.w, s, z, mn, mx);
  p[i] = x;
}

// ---------- launch ----------

extern "C" void kernel_launch(void* const* d_in, const int* in_sizes, int n_in,
                              void* d_out, int out_size, void* d_ws, size_t ws_size,
                              hipStream_t stream){
  const float* q = (const float*)d_in[0];
  const float* k = (const float*)d_in[1];
  const float* v = (const float*)d_in[2];
  const int* bits = (const int*)d_in[3];
  float* ctx = (float*)d_out;                      // also hosts per-row {Jmax,Z} stash (d=0,1)
  float* att = (float*)d_out + CTX_ELEMS;          // att_q output (written once, in pass3)
  unsigned* slots = (unsigned*)d_ws;               // 768 uints (3072 B)
  int* jmn = (int*)((char*)d_ws + 3072);           // 64 ints
  int* jmx = (int*)((char*)d_ws + 3328);           // 64 ints
  float* params = (float*)((char*)d_ws + 3584);    // 24 floats (<4 KB total)

  hipLaunchKernelGGL(init_slots_kernel, dim3(1), dim3(256), 0, stream, slots, jmn, jmx);
  hipLaunchKernelGGL(minmax3_kernel, dim3(512, 3), dim3(256), 0, stream, q, k, v, slots);
  hipLaunchKernelGGL(finalize_kernel, dim3(1), dim3(1), 0, stream, slots, jmn, jmx, params, bits, 0, 3);
  hipLaunchKernelGGL(pass1_kernel, dim3(16, BHN), dim3(256), 0, stream, q, k, params, ctx, jmn, jmx);
  hipLaunchKernelGGL(finalize_kernel, dim3(1), dim3(1), 0, stream, slots, jmn, jmx, params, bits, 3, 4);
  hipLaunchKernelGGL(pass2_kernel, dim3(16, BHN), dim3(256), 0, stream, q, k, params, ctx, slots);
  hipLaunchKernelGGL(finalize_kernel, dim3(1), dim3(1), 0, stream, slots, jmn, jmx, params, bits, 4, 5);
  hipLaunchKernelGGL(pass3_kernel, dim3(16, BHN), dim3(256), 0, stream, q, k, v, params, att, ctx, slots);
  hipLaunchKernelGGL(finalize_kernel, dim3(1), dim3(1), 0, stream, slots, jmn, jmx, params, bits, 5, 6);
  hipLaunchKernelGGL(quantctx_kernel, dim3(4096), dim3(256), 0, stream, ctx, params);
}

// Round 6
// 238.073 us; speedup vs baseline: 6.0292x; 1.3153x over previous
//
#include <hip/hip_runtime.h>
#include <cstdint>
#include <cstddef>

// Problem shape (fixed by setup_inputs): B=8, W=1024, H=8, D=64
#define W  1024
#define NH 8
#define NB 8
#define DH 64
#define BHN (NB*NH)                      // 64 batch-heads
#define CTX_ELEMS ((size_t)NB*W*NH*DH)   // 4194304
#define NS 64                            // atomic spread width
#define ROWF 512                         // row stride in floats (NH*DH)

typedef int v4i __attribute__((ext_vector_type(4)));

// ---------- helpers ----------

__device__ __forceinline__ unsigned enc_f(float f){
  unsigned u = __float_as_uint(f);
  return (u & 0x80000000u) ? ~u : (u | 0x80000000u);
}
__device__ __forceinline__ float dec_f(unsigned k){
  unsigned u = (k & 0x80000000u) ? (k ^ 0x80000000u) : ~k;
  return __uint_as_float(u);
}

// exact-division fake-quant (kept for final ctx quant — matches reference bitwise)
__device__ __forceinline__ float fq1(float x, float s, float z, float mn, float mx){
  float t = rintf(x / s) + z;
  t = fminf(fmaxf(t, mn), mx);
  return (t - z) * s;
}
// reciprocal-multiply quantize to integer level (hot paths)
__device__ __forceinline__ int qint_m(float x, float is, float z, float mn, float mx){
  return (int)fminf(fmaxf(rintf(x * is) + z, mn), mx);
}
__device__ __forceinline__ unsigned pack4(int a0, int a1, int a2, int a3){
  return (unsigned)(a0 & 0xff) | ((unsigned)(a1 & 0xff) << 8) |
         ((unsigned)(a2 & 0xff) << 16) | ((unsigned)(a3 & 0xff) << 24);
}

__device__ __forceinline__ unsigned* slot_min(unsigned* s, int t){ return s + (size_t)(2*t)*NS; }
__device__ __forceinline__ unsigned* slot_max(unsigned* s, int t){ return s + (size_t)(2*t+1)*NS; }

__device__ __forceinline__ void blk_minmax_atomic(float lmin, float lmax,
                                                  unsigned* smin, unsigned* smax){
  #pragma unroll
  for (int o = 32; o; o >>= 1){
    lmin = fminf(lmin, __shfl_xor(lmin, o));
    lmax = fmaxf(lmax, __shfl_xor(lmax, o));
  }
  __shared__ float wmn[4], wmx[4];
  int wid = threadIdx.x >> 6, lane = threadIdx.x & 63;
  if (lane == 0){ wmn[wid] = lmin; wmx[wid] = lmax; }
  __syncthreads();
  if (threadIdx.x == 0){
    float a = wmn[0], b = wmx[0];
    for (int w = 1; w < (int)(blockDim.x >> 6); ++w){
      a = fminf(a, wmn[w]); b = fmaxf(b, wmx[w]);
    }
    atomicMin(smin, enc_f(a));
    atomicMax(smax, enc_f(b));
  }
}

__device__ __forceinline__ void blk_iminmax_atomic(int lmin, int lmax, int* gmin, int* gmax){
  #pragma unroll
  for (int o = 32; o; o >>= 1){
    lmin = min(lmin, __shfl_xor(lmin, o));
    lmax = max(lmax, __shfl_xor(lmax, o));
  }
  __shared__ int iwmn[4], iwmx[4];
  int wid = threadIdx.x >> 6, lane = threadIdx.x & 63;
  if (lane == 0){ iwmn[wid] = lmin; iwmx[wid] = lmax; }
  __syncthreads();
  if (threadIdx.x == 0){
    int a = iwmn[0], b = iwmx[0];
    for (int w = 1; w < (int)(blockDim.x >> 6); ++w){
      a = min(a, iwmn[w]); b = max(b, iwmx[w]);
    }
    atomicMin(gmin, a);
    atomicMax(gmax, b);
  }
}

// stage a 64-row x 64-d fp32 tile -> int8 LDS [row][d] (+row sums via 4-lane shfl)
__device__ __forceinline__ void stage_tile(const float* __restrict__ rowptr,
                                           signed char (*S)[80], int* __restrict__ Ssum,
                                           float is, float z, float mn, float mx, int t){
  const int rr = t >> 2, dq = (t & 3) << 4;
  const float* p = rowptr + (size_t)rr * ROWF + dq;
  int part = 0;
  #pragma unroll
  for (int g = 0; g < 4; ++g){
    float4 x = *(const float4*)(p + g * 4);
    int a0 = qint_m(x.x, is, z, mn, mx), a1 = qint_m(x.y, is, z, mn, mx);
    int a2 = qint_m(x.z, is, z, mn, mx), a3 = qint_m(x.w, is, z, mn, mx);
    part += a0 + a1 + a2 + a3;
    *(unsigned*)&S[rr][dq + g*4] = pack4(a0, a1, a2, a3);
  }
  int x1 = part + __shfl_xor(part, 1);
  int tot = x1 + __shfl_xor(x1, 2);
  if ((t & 3) == 0) Ssum[rr] = tot;
}

// ---------- kernels ----------

__global__ void init_slots_kernel(unsigned* __restrict__ slots, int* __restrict__ jmn,
                                  int* __restrict__ jmx){
  for (int i = threadIdx.x; i < 6*2*NS; i += blockDim.x)
    slots[i] = 0x80000000u;   // enc(0.0f): reference clamps min<=0<=max
  if (threadIdx.x < NS){
    jmn[threadIdx.x] = 0x7fffffff;
    jmx[threadIdx.x] = (int)0x80000000;
  }
}

__global__ __launch_bounds__(256) void minmax3_kernel(const float* __restrict__ q,
                                                      const float* __restrict__ k,
                                                      const float* __restrict__ v,
                                                      unsigned* __restrict__ slots){
  const float4* p = (const float4*)(blockIdx.y == 0 ? q : (blockIdx.y == 1 ? k : v));
  float lmin = 0.f, lmax = 0.f;
  const int n4 = (int)(CTX_ELEMS / 4);
  for (int i = blockIdx.x * blockDim.x + threadIdx.x; i < n4; i += gridDim.x * blockDim.x){
    float4 x = p[i];
    lmin = fminf(lmin, fminf(fminf(x.x, x.y), fminf(x.z, x.w)));
    lmax = fmaxf(lmax, fmaxf(fmaxf(x.x, x.y), fmaxf(x.z, x.w)));
  }
  const int idx = blockIdx.x & (NS - 1);
  blk_minmax_atomic(lmin, lmax, slot_min(slots, blockIdx.y) + idx, slot_max(slots, blockIdx.y) + idx);
}

// params[4t..4t+3] = scale, zp, qmin, qmax (t: 0=q,1=k,2=v,3=scores,4=att,5=ctx)
__global__ void finalize_kernel(unsigned* __restrict__ slots, int* __restrict__ jmn,
                                int* __restrict__ jmx, float* __restrict__ params,
                                const int* __restrict__ bits_p, int t0, int t1){
  if (threadIdx.x == 0 && blockIdx.x == 0){
    int bits = *bits_p;
    float qmn = -(float)(1 << (bits - 1));
    float qmx = (float)((1 << (bits - 1)) - 1);
    for (int t = t0; t < t1; ++t){
      float mn, mx;
      if (t == 3){
        int em = jmn[0], ex = jmx[0];
        for (int i = 1; i < NS; ++i){ em = min(em, jmn[i]); ex = max(ex, jmx[i]); }
        float cfac = 0.125f * (params[0] * params[4]);
        mn = fminf(cfac * (float)em, 0.0f);
        mx = fmaxf(cfac * (float)ex, 0.0f);
      } else {
        unsigned* pm = slot_min(slots, t);
        unsigned* px = slot_max(slots, t);
        unsigned em = pm[0], ex = px[0];
        for (int i = 1; i < NS; ++i){
          em = (pm[i] < em) ? pm[i] : em;
          ex = (px[i] > ex) ? px[i] : ex;
        }
        mn = dec_f(em); mx = dec_f(ex);
      }
      float sc = fmaxf((mx - mn) / (qmx - qmn), 1e-8f);
      float zp = fminf(fmaxf(rintf(qmn - mn / sc), qmn), qmx);
      params[4*t + 0] = sc; params[4*t + 1] = zp;
      params[4*t + 2] = qmn; params[4*t + 3] = qmx;
    }
  }
}

// pass1: swapped-operand QK MFMA; per-lane fixed row i. Global J min/max + per-row Jmax.
__global__ __launch_bounds__(256) void pass1_kernel(const float* __restrict__ qg,
                                                    const float* __restrict__ kg,
                                                    const float* __restrict__ params,
                                                    float* __restrict__ stash,
                                                    int* __restrict__ jmn,
                                                    int* __restrict__ jmx){
  __shared__ __align__(16) signed char Qs[64][80], Ks[64][80];
  __shared__ int Sq[64], Sk[64];
  const int it = blockIdx.x, bh = blockIdx.y, b = bh >> 3, h = bh & 7;
  const int i0 = it << 6, t = threadIdx.x;
  const int lane = t & 63, w = t >> 6, lr = lane & 15, lg = lane >> 4;
  const float sq = params[0], zq = params[1], qmn = params[2], qmx = params[3];
  const float sk = params[4], zk = params[5];
  const float isq = 1.0f / sq, isk = 1.0f / sk;
  const int izq = (int)zq, izk = (int)zk, c64 = 64 * izq * izk;

  stage_tile(qg + ((size_t)(b*W + i0) * NH + h) * DH, Qs, Sq, isq, zq, qmn, qmx, t);
  __syncthreads();
  const v4i Bq = *(const v4i*)&Qs[(w << 4) + lr][lg << 4];
  const int sqi = Sq[(w << 4) + lr];

  int gmin = 0x7fffffff, gmax = (int)0x80000000, rmax = (int)0x80000000;
  for (int cc = 0; cc < 16; ++cc){
    __syncthreads();
    stage_tile(kg + ((size_t)(b*W + (cc << 6)) * NH + h) * DH, Ks, Sk, isk, zk, qmn, qmx, t);
    __syncthreads();
    #pragma unroll
    for (int jt = 0; jt < 4; ++jt){
      v4i Ak = *(const v4i*)&Ks[(jt << 4) + lr][lg << 4];
      v4i zz = {0, 0, 0, 0};
      v4i acc = __builtin_amdgcn_mfma_i32_16x16x64_i8(Ak, Bq, zz, 0, 0, 0);
      v4i s4 = *(const v4i*)&Sk[(jt << 4) + (lg << 2)];
      #pragma unroll
      for (int r = 0; r < 4; ++r){
        int J = acc[r] - izq * s4[r] - izk * sqi + c64;
        gmin = min(gmin, J); gmax = max(gmax, J); rmax = max(rmax, J);
      }
    }
  }
  rmax = max(rmax, __shfl_xor(rmax, 16));
  rmax = max(rmax, __shfl_xor(rmax, 32));
  if (lg == 0)
    stash[((size_t)(b*W + i0 + (w << 4) + lr) * NH + h) * DH] = __int_as_float(rmax);
  const int idx = (it + bh * 16) & (NS - 1);
  blk_iminmax_atomic(gmin, gmax, jmn + idx, jmx + idx);
}

// pass2: per-row Z via in-register exp2; global att max (=max 1/Z) -> slot 4.
__global__ __launch_bounds__(256) void pass2_kernel(const float* __restrict__ qg,
                                                    const float* __restrict__ kg,
                                                    const float* __restrict__ params,
                                                    float* __restrict__ stash,
                                                    unsigned* __restrict__ slots){
  __shared__ __align__(16) signed char Qs[64][80], Ks[64][80];
  __shared__ int Sq[64], Sk[64];
  const int it = blockIdx.x, bh = blockIdx.y, b = bh >> 3, h = bh & 7;
  const int i0 = it << 6, t = threadIdx.x;
  const int lane = t & 63, w = t >> 6, lr = lane & 15, lg = lane >> 4;
  const float sq = params[0], zq = params[1], qmn = params[2], qmx = params[3];
  const float sk = params[4], zk = params[5];
  const float ss = params[12], zs = params[13], smn = params[14], smx = params[15];
  const float isq = 1.0f / sq, isk = 1.0f / sk;
  const int izq = (int)zq, izk = (int)zk, c64 = 64 * izq * izk;
  const float rf = (0.125f * (sq * sk)) / ss;
  const float c2 = ss * 1.4426950408889634f;

  stage_tile(qg + ((size_t)(b*W + i0) * NH + h) * DH, Qs, Sq, isq, zq, qmn, qmx, t);
  __syncthreads();
  const v4i Bq = *(const v4i*)&Qs[(w << 4) + lr][lg << 4];
  const int sqi = Sq[(w << 4) + lr];
  const int irow = (w << 4) + lr;
  int Jm = __float_as_int(stash[((size_t)(b*W + i0 + irow) * NH + h) * DH]);
  const float tmxf = fminf(fmaxf(rintf((float)Jm * rf) + zs, smn), smx);

  float zacc = 0.f;
  for (int cc = 0; cc < 16; ++cc){
    __syncthreads();
    stage_tile(kg + ((size_t)(b*W + (cc << 6)) * NH + h) * DH, Ks, Sk, isk, zk, qmn, qmx, t);
    __syncthreads();
    #pragma unroll
    for (int jt = 0; jt < 4; ++jt){
      v4i Ak = *(const v4i*)&Ks[(jt << 4) + lr][lg << 4];
      v4i zz = {0, 0, 0, 0};
      v4i acc = __builtin_amdgcn_mfma_i32_16x16x64_i8(Ak, Bq, zz, 0, 0, 0);
      v4i s4 = *(const v4i*)&Sk[(jt << 4) + (lg << 2)];
      #pragma unroll
      for (int r = 0; r < 4; ++r){
        int J = acc[r] - izq * s4[r] - izk * sqi + c64;
        float tl = fminf(fmaxf(rintf((float)J * rf) + zs, smn), smx);
        zacc += exp2f((tl - tmxf) * c2);
      }
    }
  }
  zacc += __shfl_xor(zacc, 16);
  zacc += __shfl_xor(zacc, 32);
  if (lg == 0)
    stash[((size_t)(b*W + i0 + irow) * NH + h) * DH + 1] = zacc;
  float ratt = 1.0f / zacc;            // row max of softmax = exp2(0)/Z = 1/Z exactly
  #pragma unroll
  for (int o = 1; o < 16; o <<= 1) ratt = fmaxf(ratt, __shfl_xor(ratt, o));
  if (lane == 0){
    const int idx = ((it << 2) + w + bh * 64) & (NS - 1);
    atomicMax(slot_max(slots, 4) + idx, enc_f(ratt));
  }
}

// pass3: recompute J in-register, transform -> att_q (float4 out) + int8 PV-MFMA -> raw ctx.
__global__ __launch_bounds__(256) void pass3_kernel(const float* __restrict__ qg,
                                                    const float* __restrict__ kg,
                                                    const float* __restrict__ vg,
                                                    const float* __restrict__ params,
                                                    float* __restrict__ att,
                                                    float* __restrict__ ctx,
                                                    unsigned* __restrict__ slots){
  __shared__ __align__(16) signed char Qs[64][80], Ks[64][80], Vs[64][80], As[64][80];
  __shared__ int Sq[64], Sk[64];
  __shared__ int RowA[64], ColV[64];
  const int it = blockIdx.x, bh = blockIdx.y, b = bh >> 3, h = bh & 7;
  const int i0 = it << 6, t = threadIdx.x;
  const int lane = t & 63, w = t >> 6, lr = lane & 15, lg = lane >> 4;
  const float sq = params[0], zq = params[1], qmn = params[2], qmx = params[3];
  const float sk = params[4], zk = params[5];
  const float sv = params[8], zv = params[9], vmn = params[10], vmx = params[11];
  const float ss = params[12], zs = params[13], smn = params[14], smx = params[15];
  const float sa = params[16], za = params[17], amn = params[18], amx = params[19];
  const float isq = 1.0f / sq, isk = 1.0f / sk, isv = 1.0f / sv;
  const int izq = (int)zq, izk = (int)zk, c64 = 64 * izq * izk;
  const int iza = (int)za, izv = (int)zv;
  const float rf = (0.125f * (sq * sk)) / ss;
  const float c2 = ss * 1.4426950408889634f;
  const float inv_sa = 1.0f / sa;

  if (t < 64) ColV[t] = 0;
  stage_tile(qg + ((size_t)(b*W + i0) * NH + h) * DH, Qs, Sq, isq, zq, qmn, qmx, t);
  __syncthreads();
  const v4i Bq = *(const v4i*)&Qs[(w << 4) + lr][lg << 4];
  const int sqi = Sq[(w << 4) + lr];
  const int irow = (w << 4) + lr;
  const size_t rbase = ((size_t)(b*W + i0 + irow) * NH + h) * DH;
  int Jm = __float_as_int(ctx[rbase]);
  const float tmxf = fminf(fmaxf(rintf((float)Jm * rf) + zs, smn), smx);
  const float iZ = 1.0f / ctx[rbase + 1];

  const int dq4 = (t & 15) << 2;       // V: 4 d's per thread
  const int kb  = (t >> 4) << 2;       // V: 4 kk's per thread
  int cv4[4] = {0, 0, 0, 0};
  int rA = 0;
  v4i accPV[4];
  #pragma unroll
  for (int tj = 0; tj < 4; ++tj){ v4i zz = {0,0,0,0}; accPV[tj] = zz; }

  for (int cc = 0; cc < 16; ++cc){
    __syncthreads();
    stage_tile(kg + ((size_t)(b*W + (cc << 6)) * NH + h) * DH, Ks, Sk, isk, zk, qmn, qmx, t);
    {
      const float* vp = vg + ((size_t)(b*W + (cc << 6) + kb) * NH + h) * DH + dq4;
      float4 x0 = *(const float4*)(vp);
      float4 x1 = *(const float4*)(vp + ROWF);
      float4 x2 = *(const float4*)(vp + 2 * ROWF);
      float4 x3 = *(const float4*)(vp + 3 * ROWF);
      int q00 = qint_m(x0.x, isv, zv, vmn, vmx), q01 = qint_m(x0.y, isv, zv, vmn, vmx),
          q02 = qint_m(x0.z, isv, zv, vmn, vmx), q03 = qint_m(x0.w, isv, zv, vmn, vmx);
      int q10 = qint_m(x1.x, isv, zv, vmn, vmx), q11 = qint_m(x1.y, isv, zv, vmn, vmx),
          q12 = qint_m(x1.z, isv, zv, vmn, vmx), q13 = qint_m(x1.w, isv, zv, vmn, vmx);
      int q20 = qint_m(x2.x, isv, zv, vmn, vmx), q21 = qint_m(x2.y, isv, zv, vmn, vmx),
          q22 = qint_m(x2.z, isv, zv, vmn, vmx), q23 = qint_m(x2.w, isv, zv, vmn, vmx);
      int q30 = qint_m(x3.x, isv, zv, vmn, vmx), q31 = qint_m(x3.y, isv, zv, vmn, vmx),
          q32 = qint_m(x3.z, isv, zv, vmn, vmx), q33 = qint_m(x3.w, isv, zv, vmn, vmx);
      cv4[0] += q00 + q10 + q20 + q30;
      cv4[1] += q01 + q11 + q21 + q31;
      cv4[2] += q02 + q12 + q22 + q32;
      cv4[3] += q03 + q13 + q23 + q33;
      *(unsigned*)&Vs[dq4 + 0][kb] = pack4(q00, q10, q20, q30);
      *(unsigned*)&Vs[dq4 + 1][kb] = pack4(q01, q11, q21, q31);
      *(unsigned*)&Vs[dq4 + 2][kb] = pack4(q02, q12, q22, q32);
      *(unsigned*)&Vs[dq4 + 3][kb] = pack4(q03, q13, q23, q33);
    }
    __syncthreads();
    #pragma unroll
    for (int jt = 0; jt < 4; ++jt){
      v4i Ak = *(const v4i*)&Ks[(jt << 4) + lr][lg << 4];
      v4i zz = {0, 0, 0, 0};
      v4i acc = __builtin_amdgcn_mfma_i32_16x16x64_i8(Ak, Bq, zz, 0, 0, 0);
      v4i s4 = *(const v4i*)&Sk[(jt << 4) + (lg << 2)];
      float4 y;
      int J0 = acc[0] - izq * s4[0] - izk * sqi + c64;
      int J1 = acc[1] - izq * s4[1] - izk * sqi + c64;
      int J2 = acc[2] - izq * s4[2] - izk * sqi + c64;
      int J3 = acc[3] - izq * s4[3] - izk * sqi + c64;
      float tl0 = fminf(fmaxf(rintf((float)J0 * rf) + zs, smn), smx);
      float tl1 = fminf(fmaxf(rintf((float)J1 * rf) + zs, smn), smx);
      float tl2 = fminf(fmaxf(rintf((float)J2 * rf) + zs, smn), smx);
      float tl3 = fminf(fmaxf(rintf((float)J3 * rf) + zs, smn), smx);
      float p0 = exp2f((tl0 - tmxf) * c2) * iZ;
      float p1 = exp2f((tl1 - tmxf) * c2) * iZ;
      float p2 = exp2f((tl2 - tmxf) * c2) * iZ;
      float p3 = exp2f((tl3 - tmxf) * c2) * iZ;
      float a0 = fminf(fmaxf(rintf(p0 * inv_sa) + za, amn), amx);
      float a1 = fminf(fmaxf(rintf(p1 * inv_sa) + za, amn), amx);
      float a2 = fminf(fmaxf(rintf(p2 * inv_sa) + za, amn), amx);
      float a3 = fminf(fmaxf(rintf(p3 * inv_sa) + za, amn), amx);
      y.x = (a0 - za) * sa; y.y = (a1 - za) * sa;
      y.z = (a2 - za) * sa; y.w = (a3 - za) * sa;
      *(float4*)(att + ((size_t)bh << 20) + (size_t)(i0 + irow) * W
                 + (cc << 6) + (jt << 4) + (lg << 2)) = y;
      int q0 = (int)a0, q1 = (int)a1, q2 = (int)a2, q3 = (int)a3;
      rA += q0 + q1 + q2 + q3;
      *(unsigned*)&As[irow][(jt << 4) + (lg << 2)] = pack4(q0, q1, q2, q3);
    }
    __syncthreads();
    {
      v4i A2 = *(const v4i*)&As[(w << 4) + lr][lg << 4];
      #pragma unroll
      for (int tj = 0; tj < 4; ++tj){
        v4i B2 = *(const v4i*)&Vs[(tj << 4) + lr][lg << 4];
        accPV[tj] = __builtin_amdgcn_mfma_i32_16x16x64_i8(A2, B2, accPV[tj], 0, 0, 0);
      }
    }
  }

  rA += __shfl_xor(rA, 16);
  rA += __shfl_xor(rA, 32);
  if (lg == 0) RowA[irow] = rA;
  #pragma unroll
  for (int j = 0; j < 4; ++j) atomicAdd(&ColV[dq4 + j], cv4[j]);
  __syncthreads();

  const float sav = sa * sv;
  float lmin = 0.f, lmax = 0.f;
  #pragma unroll
  for (int tj = 0; tj < 4; ++tj){
    const int d = (tj << 4) + lr;
    #pragma unroll
    for (int r = 0; r < 4; ++r){
      const int i = (w << 4) + (lg << 2) + r;
      int Jv = accPV[tj][r] - iza * ColV[d] - izv * RowA[i] + 1024 * iza * izv;
      float c = sav * (float)Jv;
      lmin = fminf(lmin, c); lmax = fmaxf(lmax, c);
      ctx[(((size_t)(b * W + i0 + i)) * NH + h) * DH + d] = c;
    }
  }
  const int idx = (it + bh * 16) & (NS - 1);
  blk_minmax_atomic(lmin, lmax, slot_min(slots, 5) + idx, slot_max(slots, 5) + idx);
}

__global__ __launch_bounds__(256) void quantctx_kernel(float* __restrict__ ctx,
                                                       const float* __restrict__ params){
  const float s = params[20], z = params[21], mn = params[22], mx = params[23];
  size_t i = (size_t)blockIdx.x * blockDim.x + threadIdx.x;   // float4 index
  float4* p = (float4*)ctx;
  float4 x = p[i];
  x.x = fq1(x.x, s, z, mn, mx);
  x.y = fq1(x.y, s, z, mn, mx);
  x.z = fq1(x.z, s, z, mn, mx);
  x.w = fq1(x.w, s, z, mn, mx);
  p[i] = x;
}

// ---------- launch ----------

extern "C" void kernel_launch(void* const* d_in, const int* in_sizes, int n_in,
                              void* d_out, int out_size, void* d_ws, size_t ws_size,
                              hipStream_t stream){
  const float* q = (const float*)d_in[0];
  const float* k = (const float*)d_in[1];
  const float* v = (const float*)d_in[2];
  const int* bits = (const int*)d_in[3];
  float* ctx = (float*)d_out;                      // also hosts per-row {Jmax,Z} stash (d=0,1)
  float* att = (float*)d_out + CTX_ELEMS;          // att_q output (written once, in pass3)
  unsigned* slots = (unsigned*)d_ws;               // 768 uints (3072 B)
  int* jmn = (int*)((char*)d_ws + 3072);           // 64 ints
  int* jmx = (int*)((char*)d_ws + 3328);           // 64 ints
  float* params = (float*)((char*)d_ws + 3584);    // 24 floats (<4 KB total)

  hipLaunchKernelGGL(init_slots_kernel, dim3(1), dim3(256), 0, stream, slots, jmn, jmx);
  hipLaunchKernelGGL(minmax3_kernel, dim3(512, 3), dim3(256), 0, stream, q, k, v, slots);
  hipLaunchKernelGGL(finalize_kernel, dim3(1), dim3(1), 0, stream, slots, jmn, jmx, params, bits, 0, 3);
  hipLaunchKernelGGL(pass1_kernel, dim3(16, BHN), dim3(256), 0, stream, q, k, params, ctx, jmn, jmx);
  hipLaunchKernelGGL(finalize_kernel, dim3(1), dim3(1), 0, stream, slots, jmn, jmx, params, bits, 3, 4);
  hipLaunchKernelGGL(pass2_kernel, dim3(16, BHN), dim3(256), 0, stream, q, k, params, ctx, slots);
  hipLaunchKernelGGL(finalize_kernel, dim3(1), dim3(1), 0, stream, slots, jmn, jmx, params, bits, 4, 5);
  hipLaunchKernelGGL(pass3_kernel, dim3(16, BHN), dim3(256), 0, stream, q, k, v, params, att, ctx, slots);
  hipLaunchKernelGGL(finalize_kernel, dim3(1), dim3(1), 0, stream, slots, jmn, jmx, params, bits, 5, 6);
  hipLaunchKernelGGL(quantctx_kernel, dim3(4096), dim3(256), 0, stream, ctx, params);
}